// Round 1
// baseline (3352.964 us; speedup 1.0000x reference)
//
#include <hip/hip_runtime.h>
#include <math.h>

#define NN 100000
#define EE 600000
#define RR 2
#define DD 128
#define HH 8
#define DHH 16
#define NB 8   // nodes per block in node_transform

__device__ __forceinline__ float lrelu(float v) { return v >= 0.f ? v : 0.2f * v; }

__device__ __forceinline__ float reduce16(float p) {
    p += __shfl_xor(p, 1);
    p += __shfl_xor(p, 2);
    p += __shfl_xor(p, 4);
    p += __shfl_xor(p, 8);
    return p;
}

__device__ __forceinline__ void atomicMaxF32(float* addr, float val) {
    if (val >= 0.f)
        atomicMax((int*)addr, __float_as_int(val));
    else
        atomicMin((unsigned int*)addr, (unsigned int)__float_as_int(val));
}

// ---- init: zero message accumulator (in d_out), m = -inf, den = 0 ----
__global__ void k_init(float* __restrict__ out_msg, float* __restrict__ m,
                       float* __restrict__ den) {
    int i = blockIdx.x * blockDim.x + threadIdx.x;
    int stride = gridDim.x * blockDim.x;
    for (int k = i; k < RR * NN * DD; k += stride) out_msg[k] = 0.f;
    for (int k = i; k < RR * NN * HH; k += stride) { m[k] = -INFINITY; den[k] = 0.f; }
}

// ---- prep: a = rel_emb @ Wrel  [R*256], rel_out = rel_emb @ Wprop + bprop ----
__global__ void k_prep(const float* __restrict__ rel_emb, const float* __restrict__ Wrel,
                       const float* __restrict__ Wprop, const float* __restrict__ bprop,
                       float* __restrict__ avec, float* __restrict__ rel_out) {
    int tid = threadIdx.x;
    for (int idx = tid; idx < RR * 256; idx += 256) {
        int r = idx >> 8, o = idx & 255;
        float acc = 0.f;
        for (int i = 0; i < 64; ++i)
            acc += rel_emb[r * 64 + i] * Wrel[(r * 64 + i) * 256 + o];
        avec[idx] = acc;
    }
    {   // rel_out: 256 outputs, one per thread
        int r = tid >> 7, o = tid & 127;
        float acc = bprop[tid];
        for (int i = 0; i < 64; ++i)
            acc += rel_emb[r * 64 + i] * Wprop[(r * 64 + i) * 128 + o];
        rel_out[tid] = acc;
    }
}

// ---- fused node transform: xp -> h -> res, s_r, sc_src, sc_dst ----
__global__ __launch_bounds__(128) void k_node(
    const float* __restrict__ x, const float* __restrict__ Wp, const float* __restrict__ bp,
    const float* __restrict__ Wn, const float* __restrict__ bn,
    const float* __restrict__ Wsrc, const float* __restrict__ bsrc,
    const float* __restrict__ resW, const float* __restrict__ resb,
    const float* __restrict__ avec,
    float* __restrict__ s_out, float* __restrict__ res_out,
    float* __restrict__ sc_src, float* __restrict__ sc_dst) {
    __shared__ float xs[NB][DD];   // x rows, later h rows
    __shared__ float xps[NB][DD];  // xp rows
    const int tid = threadIdx.x;
    const int n0 = blockIdx.x * NB;
    const int head = tid >> 4;
    const int d = tid & 15;

    #pragma unroll
    for (int i = 0; i < NB; ++i) xs[i][tid] = x[(size_t)(n0 + i) * DD + tid];
    __syncthreads();

    float acc[NB];
    // xp = x @ Wp + bp
    #pragma unroll
    for (int i = 0; i < NB; ++i) acc[i] = bp[tid];
    for (int k = 0; k < DD; ++k) {
        float w = Wp[k * DD + tid];
        #pragma unroll
        for (int i = 0; i < NB; ++i) acc[i] = fmaf(xs[i][k], w, acc[i]);
    }
    #pragma unroll
    for (int i = 0; i < NB; ++i) xps[i][tid] = acc[i];
    __syncthreads();

    // h = xp @ Wn + bn  -> overwrite xs
    #pragma unroll
    for (int i = 0; i < NB; ++i) acc[i] = bn[tid];
    for (int k = 0; k < DD; ++k) {
        float w = Wn[k * DD + tid];
        #pragma unroll
        for (int i = 0; i < NB; ++i) acc[i] = fmaf(xps[i][k], w, acc[i]);
    }
    #pragma unroll
    for (int i = 0; i < NB; ++i) xs[i][tid] = acc[i];
    __syncthreads();

    // res = xp @ resW + resb
    #pragma unroll
    for (int i = 0; i < NB; ++i) acc[i] = resb[tid];
    for (int k = 0; k < DD; ++k) {
        float w = resW[k * DD + tid];
        #pragma unroll
        for (int i = 0; i < NB; ++i) acc[i] = fmaf(xps[i][k], w, acc[i]);
    }
    #pragma unroll
    for (int i = 0; i < NB; ++i) res_out[(size_t)(n0 + i) * DD + tid] = acc[i];

    // sc_dst[r][n][head] = sum_d h * a[r][head][1][d]
    #pragma unroll
    for (int r = 0; r < RR; ++r) {
        float a1 = avec[r * 256 + head * 32 + 16 + d];
        #pragma unroll
        for (int i = 0; i < NB; ++i) {
            float p = reduce16(xs[i][tid] * a1);
            if (d == 0) sc_dst[(size_t)(r * NN + n0 + i) * HH + head] = p;
        }
    }

    // s_r = h @ Wsrc[r] + bsrc[r]; sc_src[r][n][head]
    #pragma unroll
    for (int r = 0; r < RR; ++r) {
        float a0 = avec[r * 256 + head * 32 + d];
        #pragma unroll
        for (int i = 0; i < NB; ++i) acc[i] = bsrc[r * DD + tid];
        const float* W = Wsrc + (size_t)r * DD * DD;
        for (int k = 0; k < DD; ++k) {
            float w = W[k * DD + tid];
            #pragma unroll
            for (int i = 0; i < NB; ++i) acc[i] = fmaf(xs[i][k], w, acc[i]);
        }
        #pragma unroll
        for (int i = 0; i < NB; ++i) {
            s_out[(size_t)(r * NN + n0 + i) * DD + tid] = acc[i];
            float p = reduce16(acc[i] * a0);
            if (d == 0) sc_src[(size_t)(r * NN + n0 + i) * HH + head] = p;
        }
    }
}

// ---- edge pass 1: segment max (atomic) ----
__global__ void k_edge_max(const int* __restrict__ src, const int* __restrict__ dst,
                           const float* __restrict__ sc_src, const float* __restrict__ sc_dst,
                           float* __restrict__ m) {
    int e = blockIdx.x * blockDim.x + threadIdx.x;
    int r = blockIdx.y;
    if (e >= EE) return;
    int sr = src[r * EE + e], dr = dst[r * EE + e];
    const float* ss = sc_src + (size_t)(r * NN + sr) * HH;
    const float* sd = sc_dst + (size_t)(r * NN + dr) * HH;
    float* mrow = m + (size_t)(r * NN + dr) * HH;
    #pragma unroll
    for (int h = 0; h < HH; ++h) {
        float v = lrelu(ss[h] + sd[h]);
        atomicMaxF32(mrow + h, v);
    }
}

// ---- edge pass 2: denominator (atomic add of exp) ----
__global__ void k_edge_den(const int* __restrict__ src, const int* __restrict__ dst,
                           const float* __restrict__ sc_src, const float* __restrict__ sc_dst,
                           const float* __restrict__ m, float* __restrict__ den) {
    int e = blockIdx.x * blockDim.x + threadIdx.x;
    int r = blockIdx.y;
    if (e >= EE) return;
    int sr = src[r * EE + e], dr = dst[r * EE + e];
    const float* ss = sc_src + (size_t)(r * NN + sr) * HH;
    const float* sd = sc_dst + (size_t)(r * NN + dr) * HH;
    const float* mrow = m + (size_t)(r * NN + dr) * HH;
    float* drow = den + (size_t)(r * NN + dr) * HH;
    #pragma unroll
    for (int h = 0; h < HH; ++h) {
        float v = lrelu(ss[h] + sd[h]);
        atomicAdd(drow + h, __expf(v - mrow[h]));
    }
}

// ---- edge pass 3: alpha * s[src] scatter-add into out msg (d_out) ----
// 32 threads per edge, each thread does 4 columns (float4 gather).
__global__ __launch_bounds__(256) void k_edge_scatter(
    const int* __restrict__ src, const int* __restrict__ dst,
    const float* __restrict__ sc_src, const float* __restrict__ sc_dst,
    const float* __restrict__ m, const float* __restrict__ den,
    const float* __restrict__ s, float* __restrict__ out) {
    int gid = blockIdx.x * blockDim.x + threadIdx.x;
    int e = gid >> 5;
    int r = blockIdx.y;
    if (e >= EE) return;
    int j = threadIdx.x & 31;
    int h = j >> 2;
    int sr = src[r * EE + e], dr = dst[r * EE + e];
    float ss = sc_src[(size_t)(r * NN + sr) * HH + h];
    float sd = sc_dst[(size_t)(r * NN + dr) * HH + h];
    float v = lrelu(ss + sd);
    float mm = m[(size_t)(r * NN + dr) * HH + h];
    float dd = den[(size_t)(r * NN + dr) * HH + h];
    float alpha = __expf(v - mm) / dd;
    float4 s4 = *(const float4*)(s + (size_t)(r * NN + sr) * DD + j * 4);
    float* o = out + (size_t)r * NN * DD + (size_t)dr * DD + j * 4;
    atomicAdd(o + 0, alpha * s4.x);
    atomicAdd(o + 1, alpha * s4.y);
    atomicAdd(o + 2, alpha * s4.z);
    atomicAdd(o + 3, alpha * s4.w);
}

// ---- gate (sigmoid residual) + relation crossing, in-place on d_out ----
__global__ __launch_bounds__(256) void k_gate_cross(
    const float* msg,  // aliases out -- no restrict
    const float* __restrict__ res_buf, const float* __restrict__ res_alpha,
    const float* __restrict__ crossW, float* out) {
    int tid = threadIdx.x;
    int n = blockIdx.x * 2 + (tid >> 7);
    int c = tid & 127;
    float g = 1.f / (1.f + __expf(-res_alpha[0]));
    float o0 = msg[(size_t)n * DD + c];
    float o1 = msg[(size_t)NN * DD + (size_t)n * DD + c];
    float rs = res_buf[(size_t)n * DD + c];
    float og0 = o0 * g + rs * (1.f - g);
    float og1 = o1 * g + rs * (1.f - g);
    #pragma unroll
    for (int q = 0; q < 2; ++q) {
        float cw = crossW[q * DD + c];
        float l0 = lrelu(reduce16(og0 * cw));
        float l1 = lrelu(reduce16(og1 * cw));
        float mx = fmaxf(l0, l1);
        float e0 = __expf(l0 - mx), e1 = __expf(l1 - mx);
        float inv = 1.f / (e0 + e1);
        out[(size_t)q * NN * DD + (size_t)n * DD + c] = (e0 * og0 + e1 * og1) * inv;
    }
}

extern "C" void kernel_launch(void* const* d_in, const int* in_sizes, int n_in,
                              void* d_out, int out_size, void* d_ws, size_t ws_size,
                              hipStream_t stream) {
    const float* x        = (const float*)d_in[0];
    const int*   src      = (const int*)d_in[1];
    const int*   dst      = (const int*)d_in[2];
    const float* rel_emb  = (const float*)d_in[3];
    const float* Wp       = (const float*)d_in[4];
    const float* bp       = (const float*)d_in[5];
    const float* Wn       = (const float*)d_in[6];
    const float* bn       = (const float*)d_in[7];
    const float* Wsrc     = (const float*)d_in[8];
    const float* bsrc     = (const float*)d_in[9];
    const float* Wrel     = (const float*)d_in[10];
    const float* resW     = (const float*)d_in[11];
    const float* resb     = (const float*)d_in[12];
    const float* res_alpha= (const float*)d_in[13];
    const float* crossW   = (const float*)d_in[14];
    const float* Wprop    = (const float*)d_in[15];
    const float* bprop    = (const float*)d_in[16];

    float* out = (float*)d_out;
    float* ws  = (float*)d_ws;

    // workspace layout (floats)
    float* s_buf   = ws;                         // R*N*D   = 25,600,000
    float* res_buf = s_buf   + (size_t)RR * NN * DD;   // N*D = 12,800,000
    float* sc_src  = res_buf + (size_t)NN * DD;        // R*N*H = 1,600,000
    float* sc_dst  = sc_src  + (size_t)RR * NN * HH;
    float* m_buf   = sc_dst  + (size_t)RR * NN * HH;
    float* den_buf = m_buf   + (size_t)RR * NN * HH;
    float* avec    = den_buf + (size_t)RR * NN * HH;   // R*256

    k_init<<<2048, 256, 0, stream>>>(out, m_buf, den_buf);
    k_prep<<<1, 256, 0, stream>>>(rel_emb, Wrel, Wprop, bprop, avec,
                                  out + (size_t)RR * NN * DD);
    k_node<<<NN / NB, 128, 0, stream>>>(x, Wp, bp, Wn, bn, Wsrc, bsrc, resW, resb,
                                        avec, s_buf, res_buf, sc_src, sc_dst);
    dim3 eg((EE + 255) / 256, RR);
    k_edge_max<<<eg, 256, 0, stream>>>(src, dst, sc_src, sc_dst, m_buf);
    k_edge_den<<<eg, 256, 0, stream>>>(src, dst, sc_src, sc_dst, m_buf, den_buf);
    dim3 sg(EE / 8, RR);
    k_edge_scatter<<<sg, 256, 0, stream>>>(src, dst, sc_src, sc_dst, m_buf, den_buf,
                                           s_buf, out);
    k_gate_cross<<<NN / 2, 256, 0, stream>>>(out, res_buf, res_alpha, crossW, out);
}

// Round 2
// 1242.339 us; speedup vs baseline: 2.6989x; 2.6989x over previous
//
#include <hip/hip_runtime.h>
#include <math.h>

#define NN 100000
#define EE 600000
#define RR 2
#define DD 128
#define HH 8
#define DHH 16
#define NB 8   // nodes per block in node_transform
#define RN (RR * NN)

__device__ __forceinline__ float lrelu(float v) { return v >= 0.f ? v : 0.2f * v; }

__device__ __forceinline__ float reduce16(float p) {
    p += __shfl_xor(p, 1);
    p += __shfl_xor(p, 2);
    p += __shfl_xor(p, 4);
    p += __shfl_xor(p, 8);
    return p;
}

// ---- prep: a = rel_emb @ Wrel  [R*256], rel_out = rel_emb @ Wprop + bprop ----
__global__ void k_prep(const float* __restrict__ rel_emb, const float* __restrict__ Wrel,
                       const float* __restrict__ Wprop, const float* __restrict__ bprop,
                       float* __restrict__ avec, float* __restrict__ rel_out) {
    int tid = threadIdx.x;
    for (int idx = tid; idx < RR * 256; idx += 256) {
        int r = idx >> 8, o = idx & 255;
        float acc = 0.f;
        for (int i = 0; i < 64; ++i)
            acc += rel_emb[r * 64 + i] * Wrel[(r * 64 + i) * 256 + o];
        avec[idx] = acc;
    }
    {   // rel_out: 256 outputs, one per thread
        int r = tid >> 7, o = tid & 127;
        float acc = bprop[tid];
        for (int i = 0; i < 64; ++i)
            acc += rel_emb[r * 64 + i] * Wprop[(r * 64 + i) * 128 + o];
        rel_out[tid] = acc;
    }
}

// ---- fused node transform: xp -> h -> res, s_r, sc_src, sc_dst ----
__global__ __launch_bounds__(128) void k_node(
    const float* __restrict__ x, const float* __restrict__ Wp, const float* __restrict__ bp,
    const float* __restrict__ Wn, const float* __restrict__ bn,
    const float* __restrict__ Wsrc, const float* __restrict__ bsrc,
    const float* __restrict__ resW, const float* __restrict__ resb,
    const float* __restrict__ avec,
    float* __restrict__ s_out, float* __restrict__ res_out,
    float* __restrict__ sc_src, float* __restrict__ sc_dst) {
    __shared__ float xs[NB][DD];   // x rows, later h rows
    __shared__ float xps[NB][DD];  // xp rows
    const int tid = threadIdx.x;
    const int n0 = blockIdx.x * NB;
    const int head = tid >> 4;
    const int d = tid & 15;

    #pragma unroll
    for (int i = 0; i < NB; ++i) xs[i][tid] = x[(size_t)(n0 + i) * DD + tid];
    __syncthreads();

    float acc[NB];
    // xp = x @ Wp + bp
    #pragma unroll
    for (int i = 0; i < NB; ++i) acc[i] = bp[tid];
    for (int k = 0; k < DD; ++k) {
        float w = Wp[k * DD + tid];
        #pragma unroll
        for (int i = 0; i < NB; ++i) acc[i] = fmaf(xs[i][k], w, acc[i]);
    }
    #pragma unroll
    for (int i = 0; i < NB; ++i) xps[i][tid] = acc[i];
    __syncthreads();

    // h = xp @ Wn + bn  -> overwrite xs
    #pragma unroll
    for (int i = 0; i < NB; ++i) acc[i] = bn[tid];
    for (int k = 0; k < DD; ++k) {
        float w = Wn[k * DD + tid];
        #pragma unroll
        for (int i = 0; i < NB; ++i) acc[i] = fmaf(xps[i][k], w, acc[i]);
    }
    #pragma unroll
    for (int i = 0; i < NB; ++i) xs[i][tid] = acc[i];
    __syncthreads();

    // res = xp @ resW + resb
    #pragma unroll
    for (int i = 0; i < NB; ++i) acc[i] = resb[tid];
    for (int k = 0; k < DD; ++k) {
        float w = resW[k * DD + tid];
        #pragma unroll
        for (int i = 0; i < NB; ++i) acc[i] = fmaf(xps[i][k], w, acc[i]);
    }
    #pragma unroll
    for (int i = 0; i < NB; ++i) res_out[(size_t)(n0 + i) * DD + tid] = acc[i];

    // sc_dst[r][n][head] = sum_d h * a[r][head][1][d]
    #pragma unroll
    for (int r = 0; r < RR; ++r) {
        float a1 = avec[r * 256 + head * 32 + 16 + d];
        #pragma unroll
        for (int i = 0; i < NB; ++i) {
            float p = reduce16(xs[i][tid] * a1);
            if (d == 0) sc_dst[(size_t)(r * NN + n0 + i) * HH + head] = p;
        }
    }

    // s_r = h @ Wsrc[r] + bsrc[r]; sc_src[r][n][head]
    #pragma unroll
    for (int r = 0; r < RR; ++r) {
        float a0 = avec[r * 256 + head * 32 + d];
        #pragma unroll
        for (int i = 0; i < NB; ++i) acc[i] = bsrc[r * DD + tid];
        const float* W = Wsrc + (size_t)r * DD * DD;
        for (int k = 0; k < DD; ++k) {
            float w = W[k * DD + tid];
            #pragma unroll
            for (int i = 0; i < NB; ++i) acc[i] = fmaf(xs[i][k], w, acc[i]);
        }
        #pragma unroll
        for (int i = 0; i < NB; ++i) {
            s_out[(size_t)(r * NN + n0 + i) * DD + tid] = acc[i];
            float p = reduce16(acc[i] * a0);
            if (d == 0) sc_src[(size_t)(r * NN + n0 + i) * HH + head] = p;
        }
    }
}

// ---- CSR build ----
__global__ void k_zero(int* __restrict__ cnt) {
    int i = blockIdx.x * blockDim.x + threadIdx.x;
    if (i < RN) cnt[i] = 0;
}

__global__ void k_count(const int* __restrict__ dst, int* __restrict__ cnt) {
    int idx = blockIdx.x * blockDim.x + threadIdx.x;
    if (idx >= RR * EE) return;
    int r = idx / EE;
    atomicAdd(&cnt[r * NN + dst[idx]], 1);
}

// single-block exclusive scan over RN counts -> row_ptr, cursor
__global__ __launch_bounds__(1024) void k_scan(const int* __restrict__ cnt,
                                               int* __restrict__ row_ptr,
                                               int* __restrict__ cursor) {
    __shared__ int part[1024];
    const int tid = threadIdx.x;
    const int per = (RN + 1023) / 1024;
    const int base = tid * per;
    int sum = 0;
    for (int i = 0; i < per; ++i) {
        int idx = base + i;
        if (idx < RN) sum += cnt[idx];
    }
    part[tid] = sum;
    __syncthreads();
    for (int off = 1; off < 1024; off <<= 1) {
        int v = 0;
        if (tid >= off) v = part[tid - off];
        __syncthreads();
        if (tid >= off) part[tid] += v;
        __syncthreads();
    }
    int run = (tid == 0) ? 0 : part[tid - 1];
    for (int i = 0; i < per; ++i) {
        int idx = base + i;
        if (idx < RN) {
            row_ptr[idx] = run;
            cursor[idx] = run;
            run += cnt[idx];
        }
    }
    if (tid == 1023) row_ptr[RN] = run;
}

__global__ void k_fill(const int* __restrict__ dst, int* __restrict__ cursor,
                       int* __restrict__ eid) {
    int idx = blockIdx.x * blockDim.x + threadIdx.x;
    if (idx >= RR * EE) return;
    int r = idx / EE;
    int e = idx - r * EE;
    int pos = atomicAdd(&cursor[r * NN + dst[idx]], 1);
    eid[pos] = e;
}

// deterministic order within each segment (selection sort by edge id)
__global__ void k_sortseg(const int* __restrict__ row_ptr, int* __restrict__ eid) {
    int s = blockIdx.x * blockDim.x + threadIdx.x;
    if (s >= RN) return;
    int p0 = row_ptr[s], p1 = row_ptr[s + 1];
    for (int i = p0; i < p1 - 1; ++i) {
        int mn = eid[i], mi = i;
        for (int k = i + 1; k < p1; ++k) {
            int v = eid[k];
            if (v < mn) { mn = v; mi = k; }
        }
        eid[mi] = eid[i];
        eid[i] = mn;
    }
}

// ---- fused gather: segment softmax + message agg + gate + relation crossing ----
// One wave64 per node: lanes 0-31 -> relation 0, lanes 32-63 -> relation 1.
// Lane j (0..31) within group handles columns 4j..4j+3 (head h = j>>2).
__global__ __launch_bounds__(256) void k_gather_cross(
    const int* __restrict__ src, const int* __restrict__ row_ptr,
    const int* __restrict__ eid,
    const float* __restrict__ sc_src, const float* __restrict__ sc_dst,
    const float* __restrict__ s, const float* __restrict__ res_buf,
    const float* __restrict__ res_alpha, const float* __restrict__ crossW,
    float* __restrict__ out) {
    int n = blockIdx.x * 4 + (threadIdx.x >> 6);
    if (n >= NN) return;
    const int lane = threadIdx.x & 63;
    const int g = lane >> 5;   // relation of this half-wave
    const int j = lane & 31;   // column quad: cols 4j..4j+3
    const int h = j >> 2;

    const int seg = g * NN + n;
    const int p0 = row_ptr[seg], p1 = row_ptr[seg + 1];
    const float sd = sc_dst[(size_t)seg * HH + h];

    // pass 1: segment max
    float mx = -INFINITY;
    for (int p = p0; p < p1; ++p) {
        int sr = src[g * EE + eid[p]];
        float v = lrelu(sc_src[(size_t)(g * NN + sr) * HH + h] + sd);
        mx = fmaxf(mx, v);
    }
    // pass 2: exp-sum + weighted accumulate
    float den = 0.f;
    float4 acc = {0.f, 0.f, 0.f, 0.f};
    for (int p = p0; p < p1; ++p) {
        int sr = src[g * EE + eid[p]];
        float v = lrelu(sc_src[(size_t)(g * NN + sr) * HH + h] + sd);
        float e = __expf(v - mx);
        den += e;
        float4 s4 = *(const float4*)(s + (size_t)(g * NN + sr) * DD + j * 4);
        acc.x = fmaf(e, s4.x, acc.x);
        acc.y = fmaf(e, s4.y, acc.y);
        acc.z = fmaf(e, s4.z, acc.z);
        acc.w = fmaf(e, s4.w, acc.w);
    }
    float inv = (p1 > p0) ? 1.f / den : 0.f;

    // sigmoid gate with residual
    float gate = 1.f / (1.f + __expf(-res_alpha[0]));
    float4 r4 = *(const float4*)(res_buf + (size_t)n * DD + j * 4);
    float4 og;
    og.x = fmaf(acc.x * inv, gate, r4.x * (1.f - gate));
    og.y = fmaf(acc.y * inv, gate, r4.y * (1.f - gate));
    og.z = fmaf(acc.z * inv, gate, r4.z * (1.f - gate));
    og.w = fmaf(acc.w * inv, gate, r4.w * (1.f - gate));

    // relation crossing: this half computes fused output for q = g
    float4 oo;  // other relation's og
    oo.x = __shfl_xor(og.x, 32);
    oo.y = __shfl_xor(og.y, 32);
    oo.z = __shfl_xor(og.z, 32);
    oo.w = __shfl_xor(og.w, 32);

    float4 cw = *(const float4*)(crossW + g * DD + j * 4);
    float ds_ = og.x * cw.x + og.y * cw.y + og.z * cw.z + og.w * cw.w;
    float do_ = oo.x * cw.x + oo.y * cw.y + oo.z * cw.z + oo.w * cw.w;
    // reduce over the 4 lanes of this head (cols 16)
    ds_ += __shfl_xor(ds_, 1); ds_ += __shfl_xor(ds_, 2);
    do_ += __shfl_xor(do_, 1); do_ += __shfl_xor(do_, 2);
    float l0 = lrelu(ds_), l1 = lrelu(do_);
    float mm = fmaxf(l0, l1);
    float e0 = __expf(l0 - mm), e1 = __expf(l1 - mm);
    float winv = 1.f / (e0 + e1);
    float w0 = e0 * winv, w1 = e1 * winv;

    float4 o;
    o.x = w0 * og.x + w1 * oo.x;
    o.y = w0 * og.y + w1 * oo.y;
    o.z = w0 * og.z + w1 * oo.z;
    o.w = w0 * og.w + w1 * oo.w;
    *(float4*)(out + (size_t)(g * NN + n) * DD + j * 4) = o;
}

extern "C" void kernel_launch(void* const* d_in, const int* in_sizes, int n_in,
                              void* d_out, int out_size, void* d_ws, size_t ws_size,
                              hipStream_t stream) {
    const float* x        = (const float*)d_in[0];
    const int*   src      = (const int*)d_in[1];
    const int*   dst      = (const int*)d_in[2];
    const float* rel_emb  = (const float*)d_in[3];
    const float* Wp       = (const float*)d_in[4];
    const float* bp       = (const float*)d_in[5];
    const float* Wn       = (const float*)d_in[6];
    const float* bn       = (const float*)d_in[7];
    const float* Wsrc     = (const float*)d_in[8];
    const float* bsrc     = (const float*)d_in[9];
    const float* Wrel     = (const float*)d_in[10];
    const float* resW     = (const float*)d_in[11];
    const float* resb     = (const float*)d_in[12];
    const float* res_alpha= (const float*)d_in[13];
    const float* crossW   = (const float*)d_in[14];
    const float* Wprop    = (const float*)d_in[15];
    const float* bprop    = (const float*)d_in[16];

    float* out = (float*)d_out;
    float* ws  = (float*)d_ws;

    // workspace layout
    float* s_buf   = ws;                                  // R*N*D   = 25,600,000 f
    float* res_buf = s_buf   + (size_t)RR * NN * DD;      // N*D     = 12,800,000 f
    float* sc_src  = res_buf + (size_t)NN * DD;           // R*N*H   =  1,600,000 f
    float* sc_dst  = sc_src  + (size_t)RR * NN * HH;      // R*N*H
    float* avec    = sc_dst  + (size_t)RR * NN * HH;      // 512 f
    int*   cnt     = (int*)(avec + 512);                  // RN
    int*   row_ptr = cnt + RN;                            // RN + 1
    int*   cursor  = row_ptr + RN + 1;                    // RN
    int*   eid     = cursor + RN;                         // R*E = 1,200,000

    k_prep<<<1, 256, 0, stream>>>(rel_emb, Wrel, Wprop, bprop, avec,
                                  out + (size_t)RR * NN * DD);
    k_node<<<NN / NB, 128, 0, stream>>>(x, Wp, bp, Wn, bn, Wsrc, bsrc, resW, resb,
                                        avec, s_buf, res_buf, sc_src, sc_dst);
    k_zero<<<(RN + 255) / 256, 256, 0, stream>>>(cnt);
    k_count<<<(RR * EE + 255) / 256, 256, 0, stream>>>(dst, cnt);
    k_scan<<<1, 1024, 0, stream>>>(cnt, row_ptr, cursor);
    k_fill<<<(RR * EE + 255) / 256, 256, 0, stream>>>(dst, cursor, eid);
    k_sortseg<<<(RN + 255) / 256, 256, 0, stream>>>(row_ptr, eid);
    k_gather_cross<<<(NN + 3) / 4, 256, 0, stream>>>(src, row_ptr, eid, sc_src, sc_dst,
                                                     s_buf, res_buf, res_alpha, crossW,
                                                     out);
}

// Round 3
// 752.392 us; speedup vs baseline: 4.4564x; 1.6512x over previous
//
#include <hip/hip_runtime.h>
#include <math.h>

#define NN 100000
#define EE 600000
#define RR 2
#define DD 128
#define HH 8
#define DHH 16
#define NB 8   // nodes per block in node_transform
#define RN (RR * NN)
#define SCAN_CHUNK 1024
#define NBLK ((RN + SCAN_CHUNK - 1) / SCAN_CHUNK)   // 196

__device__ __forceinline__ float lrelu(float v) { return v >= 0.f ? v : 0.2f * v; }

__device__ __forceinline__ float reduce16(float p) {
    p += __shfl_xor(p, 1);
    p += __shfl_xor(p, 2);
    p += __shfl_xor(p, 4);
    p += __shfl_xor(p, 8);
    return p;
}

// ---- prep: a = rel_emb @ Wrel  [R*256], rel_out = rel_emb @ Wprop + bprop ----
__global__ void k_prep(const float* __restrict__ rel_emb, const float* __restrict__ Wrel,
                       const float* __restrict__ Wprop, const float* __restrict__ bprop,
                       float* __restrict__ avec, float* __restrict__ rel_out) {
    int tid = threadIdx.x;
    for (int idx = tid; idx < RR * 256; idx += 256) {
        int r = idx >> 8, o = idx & 255;
        float acc = 0.f;
        for (int i = 0; i < 64; ++i)
            acc += rel_emb[r * 64 + i] * Wrel[(r * 64 + i) * 256 + o];
        avec[idx] = acc;
    }
    {   // rel_out: 256 outputs, one per thread
        int r = tid >> 7, o = tid & 127;
        float acc = bprop[tid];
        for (int i = 0; i < 64; ++i)
            acc += rel_emb[r * 64 + i] * Wprop[(r * 64 + i) * 128 + o];
        rel_out[tid] = acc;
    }
}

// ---- fused node transform: xp -> h -> res, s_r, sc_src, sc_dst ----
__global__ __launch_bounds__(128) void k_node(
    const float* __restrict__ x, const float* __restrict__ Wp, const float* __restrict__ bp,
    const float* __restrict__ Wn, const float* __restrict__ bn,
    const float* __restrict__ Wsrc, const float* __restrict__ bsrc,
    const float* __restrict__ resW, const float* __restrict__ resb,
    const float* __restrict__ avec,
    float* __restrict__ s_out, float* __restrict__ res_out,
    float* __restrict__ sc_src, float* __restrict__ sc_dst) {
    __shared__ float xs[NB][DD];   // x rows, later h rows
    __shared__ float xps[NB][DD];  // xp rows
    const int tid = threadIdx.x;
    const int n0 = blockIdx.x * NB;
    const int head = tid >> 4;
    const int d = tid & 15;

    #pragma unroll
    for (int i = 0; i < NB; ++i) xs[i][tid] = x[(size_t)(n0 + i) * DD + tid];
    __syncthreads();

    float acc[NB];
    // xp = x @ Wp + bp
    #pragma unroll
    for (int i = 0; i < NB; ++i) acc[i] = bp[tid];
    for (int k = 0; k < DD; ++k) {
        float w = Wp[k * DD + tid];
        #pragma unroll
        for (int i = 0; i < NB; ++i) acc[i] = fmaf(xs[i][k], w, acc[i]);
    }
    #pragma unroll
    for (int i = 0; i < NB; ++i) xps[i][tid] = acc[i];
    __syncthreads();

    // h = xp @ Wn + bn  -> overwrite xs
    #pragma unroll
    for (int i = 0; i < NB; ++i) acc[i] = bn[tid];
    for (int k = 0; k < DD; ++k) {
        float w = Wn[k * DD + tid];
        #pragma unroll
        for (int i = 0; i < NB; ++i) acc[i] = fmaf(xps[i][k], w, acc[i]);
    }
    #pragma unroll
    for (int i = 0; i < NB; ++i) xs[i][tid] = acc[i];
    __syncthreads();

    // res = xp @ resW + resb
    #pragma unroll
    for (int i = 0; i < NB; ++i) acc[i] = resb[tid];
    for (int k = 0; k < DD; ++k) {
        float w = resW[k * DD + tid];
        #pragma unroll
        for (int i = 0; i < NB; ++i) acc[i] = fmaf(xps[i][k], w, acc[i]);
    }
    #pragma unroll
    for (int i = 0; i < NB; ++i) res_out[(size_t)(n0 + i) * DD + tid] = acc[i];

    // sc_dst[r][n][head] = sum_d h * a[r][head][1][d]
    #pragma unroll
    for (int r = 0; r < RR; ++r) {
        float a1 = avec[r * 256 + head * 32 + 16 + d];
        #pragma unroll
        for (int i = 0; i < NB; ++i) {
            float p = reduce16(xs[i][tid] * a1);
            if (d == 0) sc_dst[(size_t)(r * NN + n0 + i) * HH + head] = p;
        }
    }

    // s_r = h @ Wsrc[r] + bsrc[r]; sc_src[r][n][head]
    #pragma unroll
    for (int r = 0; r < RR; ++r) {
        float a0 = avec[r * 256 + head * 32 + d];
        #pragma unroll
        for (int i = 0; i < NB; ++i) acc[i] = bsrc[r * DD + tid];
        const float* W = Wsrc + (size_t)r * DD * DD;
        for (int k = 0; k < DD; ++k) {
            float w = W[k * DD + tid];
            #pragma unroll
            for (int i = 0; i < NB; ++i) acc[i] = fmaf(xs[i][k], w, acc[i]);
        }
        #pragma unroll
        for (int i = 0; i < NB; ++i) {
            s_out[(size_t)(r * NN + n0 + i) * DD + tid] = acc[i];
            float p = reduce16(acc[i] * a0);
            if (d == 0) sc_src[(size_t)(r * NN + n0 + i) * HH + head] = p;
        }
    }
}

// ---- CSR build ----
__global__ void k_zero(int* __restrict__ cnt) {
    int i = blockIdx.x * blockDim.x + threadIdx.x;
    if (i < RN) cnt[i] = 0;
}

__global__ void k_count(const int* __restrict__ dst, int* __restrict__ cnt) {
    int idx = blockIdx.x * blockDim.x + threadIdx.x;
    if (idx >= RR * EE) return;
    int r = idx / EE;
    atomicAdd(&cnt[r * NN + dst[idx]], 1);
}

// hierarchical scan, stage 1: per-block exclusive scan + block totals
__global__ __launch_bounds__(SCAN_CHUNK) void k_scan1(const int* __restrict__ cnt,
                                                      int* __restrict__ row_ptr,
                                                      int* __restrict__ blk) {
    __shared__ int sh[SCAN_CHUNK];
    const int tid = threadIdx.x;
    const int i = blockIdx.x * SCAN_CHUNK + tid;
    int v = (i < RN) ? cnt[i] : 0;
    sh[tid] = v;
    __syncthreads();
    for (int off = 1; off < SCAN_CHUNK; off <<= 1) {
        int t = (tid >= off) ? sh[tid - off] : 0;
        __syncthreads();
        sh[tid] += t;
        __syncthreads();
    }
    if (i < RN) row_ptr[i] = sh[tid] - v;   // exclusive within block
    if (tid == SCAN_CHUNK - 1) blk[blockIdx.x] = sh[tid];
}

// stage 2: single small block scans the 196 block totals (exclusive, in place)
__global__ __launch_bounds__(256) void k_scan2(int* __restrict__ blk) {
    __shared__ int sh[256];
    const int tid = threadIdx.x;
    int v = (tid < NBLK) ? blk[tid] : 0;
    sh[tid] = v;
    __syncthreads();
    for (int off = 1; off < 256; off <<= 1) {
        int t = (tid >= off) ? sh[tid - off] : 0;
        __syncthreads();
        sh[tid] += t;
        __syncthreads();
    }
    if (tid < NBLK) blk[tid] = sh[tid] - v;
}

// stage 3: add block offsets -> final row_ptr, cursor
__global__ void k_scan3(int* __restrict__ row_ptr, int* __restrict__ cursor,
                        const int* __restrict__ blk) {
    int i = blockIdx.x * blockDim.x + threadIdx.x;
    if (i < RN) {
        int v = row_ptr[i] + blk[i / SCAN_CHUNK];
        row_ptr[i] = v;
        cursor[i] = v;
    }
    if (i == 0) row_ptr[RN] = RR * EE;   // total edge count is fixed
}

__global__ void k_fill(const int* __restrict__ dst, int* __restrict__ cursor,
                       int* __restrict__ eid) {
    int idx = blockIdx.x * blockDim.x + threadIdx.x;
    if (idx >= RR * EE) return;
    int r = idx / EE;
    int e = idx - r * EE;
    int pos = atomicAdd(&cursor[r * NN + dst[idx]], 1);
    eid[pos] = e;
}

// deterministic order within each segment (selection sort by edge id)
__global__ void k_sortseg(const int* __restrict__ row_ptr, int* __restrict__ eid) {
    int s = blockIdx.x * blockDim.x + threadIdx.x;
    if (s >= RN) return;
    int p0 = row_ptr[s], p1 = row_ptr[s + 1];
    for (int i = p0; i < p1 - 1; ++i) {
        int mn = eid[i], mi = i;
        for (int k = i + 1; k < p1; ++k) {
            int v = eid[k];
            if (v < mn) { mn = v; mi = k; }
        }
        eid[mi] = eid[i];
        eid[i] = mn;
    }
}

// ---- fused gather: segment softmax + message agg + gate + relation crossing ----
// One wave64 per node: lanes 0-31 -> relation 0, lanes 32-63 -> relation 1.
// Lane j (0..31) within group handles columns 4j..4j+3 (head h = j>>2).
__global__ __launch_bounds__(256) void k_gather_cross(
    const int* __restrict__ src, const int* __restrict__ row_ptr,
    const int* __restrict__ eid,
    const float* __restrict__ sc_src, const float* __restrict__ sc_dst,
    const float* __restrict__ s, const float* __restrict__ res_buf,
    const float* __restrict__ res_alpha, const float* __restrict__ crossW,
    float* __restrict__ out) {
    int n = blockIdx.x * 4 + (threadIdx.x >> 6);
    if (n >= NN) return;
    const int lane = threadIdx.x & 63;
    const int g = lane >> 5;   // relation of this half-wave
    const int j = lane & 31;   // column quad: cols 4j..4j+3
    const int h = j >> 2;

    const int seg = g * NN + n;
    const int p0 = row_ptr[seg], p1 = row_ptr[seg + 1];
    const float sd = sc_dst[(size_t)seg * HH + h];

    // pass 1: segment max
    float mx = -INFINITY;
    for (int p = p0; p < p1; ++p) {
        int sr = src[g * EE + eid[p]];
        float v = lrelu(sc_src[(size_t)(g * NN + sr) * HH + h] + sd);
        mx = fmaxf(mx, v);
    }
    // pass 2: exp-sum + weighted accumulate
    float den = 0.f;
    float4 acc = {0.f, 0.f, 0.f, 0.f};
    for (int p = p0; p < p1; ++p) {
        int sr = src[g * EE + eid[p]];
        float v = lrelu(sc_src[(size_t)(g * NN + sr) * HH + h] + sd);
        float e = __expf(v - mx);
        den += e;
        float4 s4 = *(const float4*)(s + (size_t)(g * NN + sr) * DD + j * 4);
        acc.x = fmaf(e, s4.x, acc.x);
        acc.y = fmaf(e, s4.y, acc.y);
        acc.z = fmaf(e, s4.z, acc.z);
        acc.w = fmaf(e, s4.w, acc.w);
    }
    float inv = (p1 > p0) ? 1.f / den : 0.f;

    // sigmoid gate with residual
    float gate = 1.f / (1.f + __expf(-res_alpha[0]));
    float4 r4 = *(const float4*)(res_buf + (size_t)n * DD + j * 4);
    float4 og;
    og.x = fmaf(acc.x * inv, gate, r4.x * (1.f - gate));
    og.y = fmaf(acc.y * inv, gate, r4.y * (1.f - gate));
    og.z = fmaf(acc.z * inv, gate, r4.z * (1.f - gate));
    og.w = fmaf(acc.w * inv, gate, r4.w * (1.f - gate));

    // relation crossing: this half computes fused output for q = g
    float4 oo;  // other relation's og
    oo.x = __shfl_xor(og.x, 32);
    oo.y = __shfl_xor(og.y, 32);
    oo.z = __shfl_xor(og.z, 32);
    oo.w = __shfl_xor(og.w, 32);

    float4 cw = *(const float4*)(crossW + g * DD + j * 4);
    float ds_ = og.x * cw.x + og.y * cw.y + og.z * cw.z + og.w * cw.w;
    float do_ = oo.x * cw.x + oo.y * cw.y + oo.z * cw.z + oo.w * cw.w;
    // reduce over the 4 lanes of this head (cols 16)
    ds_ += __shfl_xor(ds_, 1); ds_ += __shfl_xor(ds_, 2);
    do_ += __shfl_xor(do_, 1); do_ += __shfl_xor(do_, 2);
    float l0 = lrelu(ds_), l1 = lrelu(do_);
    float mm = fmaxf(l0, l1);
    float e0 = __expf(l0 - mm), e1 = __expf(l1 - mm);
    float winv = 1.f / (e0 + e1);
    float w0 = e0 * winv, w1 = e1 * winv;

    float4 o;
    o.x = w0 * og.x + w1 * oo.x;
    o.y = w0 * og.y + w1 * oo.y;
    o.z = w0 * og.z + w1 * oo.z;
    o.w = w0 * og.w + w1 * oo.w;
    *(float4*)(out + (size_t)(g * NN + n) * DD + j * 4) = o;
}

extern "C" void kernel_launch(void* const* d_in, const int* in_sizes, int n_in,
                              void* d_out, int out_size, void* d_ws, size_t ws_size,
                              hipStream_t stream) {
    const float* x        = (const float*)d_in[0];
    const int*   src      = (const int*)d_in[1];
    const int*   dst      = (const int*)d_in[2];
    const float* rel_emb  = (const float*)d_in[3];
    const float* Wp       = (const float*)d_in[4];
    const float* bp       = (const float*)d_in[5];
    const float* Wn       = (const float*)d_in[6];
    const float* bn       = (const float*)d_in[7];
    const float* Wsrc     = (const float*)d_in[8];
    const float* bsrc     = (const float*)d_in[9];
    const float* Wrel     = (const float*)d_in[10];
    const float* resW     = (const float*)d_in[11];
    const float* resb     = (const float*)d_in[12];
    const float* res_alpha= (const float*)d_in[13];
    const float* crossW   = (const float*)d_in[14];
    const float* Wprop    = (const float*)d_in[15];
    const float* bprop    = (const float*)d_in[16];

    float* out = (float*)d_out;
    float* ws  = (float*)d_ws;

    // workspace layout
    float* s_buf   = ws;                                  // R*N*D   = 25,600,000 f
    float* res_buf = s_buf   + (size_t)RR * NN * DD;      // N*D     = 12,800,000 f
    float* sc_src  = res_buf + (size_t)NN * DD;           // R*N*H   =  1,600,000 f
    float* sc_dst  = sc_src  + (size_t)RR * NN * HH;      // R*N*H
    float* avec    = sc_dst  + (size_t)RR * NN * HH;      // 512 f
    int*   cnt     = (int*)(avec + 512);                  // RN
    int*   row_ptr = cnt + RN;                            // RN + 1
    int*   cursor  = row_ptr + RN + 1;                    // RN
    int*   eid     = cursor + RN;                         // R*E = 1,200,000
    int*   blk     = eid + RR * EE;                       // NBLK

    k_prep<<<1, 256, 0, stream>>>(rel_emb, Wrel, Wprop, bprop, avec,
                                  out + (size_t)RR * NN * DD);
    k_node<<<NN / NB, 128, 0, stream>>>(x, Wp, bp, Wn, bn, Wsrc, bsrc, resW, resb,
                                        avec, s_buf, res_buf, sc_src, sc_dst);
    k_zero<<<(RN + 255) / 256, 256, 0, stream>>>(cnt);
    k_count<<<(RR * EE + 255) / 256, 256, 0, stream>>>(dst, cnt);
    k_scan1<<<NBLK, SCAN_CHUNK, 0, stream>>>(cnt, row_ptr, blk);
    k_scan2<<<1, 256, 0, stream>>>(blk);
    k_scan3<<<(RN + 255) / 256, 256, 0, stream>>>(row_ptr, cursor, blk);
    k_fill<<<(RR * EE + 255) / 256, 256, 0, stream>>>(dst, cursor, eid);
    k_sortseg<<<(RN + 255) / 256, 256, 0, stream>>>(row_ptr, eid);
    k_gather_cross<<<(NN + 3) / 4, 256, 0, stream>>>(src, row_ptr, eid, sc_src, sc_dst,
                                                     s_buf, res_buf, res_alpha, crossW,
                                                     out);
}

// Round 4
// 698.055 us; speedup vs baseline: 4.8033x; 1.0778x over previous
//
#include <hip/hip_runtime.h>
#include <math.h>

#define NN 100000
#define EE 600000
#define RR 2
#define DD 128
#define HH 8
#define DHH 16
#define RN (RR * NN)
#define NB2 16   // nodes per block in node GEMM
#define SCAN_CHUNK 1024
#define NBLK ((RN + SCAN_CHUNK - 1) / SCAN_CHUNK)   // 196

__device__ __forceinline__ float lrelu(float v) { return v >= 0.f ? v : 0.2f * v; }

__device__ __forceinline__ float reduce16(float p) {
    p += __shfl_xor(p, 1);
    p += __shfl_xor(p, 2);
    p += __shfl_xor(p, 4);
    p += __shfl_xor(p, 8);
    return p;
}

// ---- prep: a = rel_emb @ Wrel  [R*256], rel_out = rel_emb @ Wprop + bprop ----
__global__ void k_prep(const float* __restrict__ rel_emb, const float* __restrict__ Wrel,
                       const float* __restrict__ Wprop, const float* __restrict__ bprop,
                       float* __restrict__ avec, float* __restrict__ rel_out) {
    int tid = threadIdx.x;
    for (int idx = tid; idx < RR * 256; idx += 256) {
        int r = idx >> 8, o = idx & 255;
        float acc = 0.f;
        for (int i = 0; i < 64; ++i)
            acc += rel_emb[r * 64 + i] * Wrel[(r * 64 + i) * 256 + o];
        avec[idx] = acc;
    }
    {   // rel_out: 256 outputs, one per thread
        int r = tid >> 7, o = tid & 127;
        float acc = bprop[tid];
        for (int i = 0; i < 64; ++i)
            acc += rel_emb[r * 64 + i] * Wprop[(r * 64 + i) * 128 + o];
        rel_out[tid] = acc;
    }
}

// ---- compose stage 1: Wpn = Wp@Wn, Wres_c = Wp@resW (+ bias folds) ----
__global__ __launch_bounds__(128) void k_compose1(
    const float* __restrict__ Wp, const float* __restrict__ bp,
    const float* __restrict__ Wn, const float* __restrict__ bn,
    const float* __restrict__ resW, const float* __restrict__ resb,
    float* __restrict__ Wpn, float* __restrict__ bpn,
    float* __restrict__ Wres_c, float* __restrict__ bres_c) {
    __shared__ float row[DD];
    const int rrow = blockIdx.x, tid = threadIdx.x;
    row[tid] = Wp[rrow * DD + tid];
    __syncthreads();
    float acc1 = 0.f, acc2 = 0.f;
    for (int k = 0; k < DD; ++k) {
        float wv = row[k];
        acc1 = fmaf(wv, Wn[k * DD + tid], acc1);
        acc2 = fmaf(wv, resW[k * DD + tid], acc2);
    }
    Wpn[rrow * DD + tid] = acc1;
    Wres_c[rrow * DD + tid] = acc2;
    if (rrow == 0) {
        float b1 = 0.f, b2 = 0.f;
        for (int k = 0; k < DD; ++k) {
            b1 = fmaf(bp[k], Wn[k * DD + tid], b1);
            b2 = fmaf(bp[k], resW[k * DD + tid], b2);
        }
        bpn[tid] = b1 + bn[tid];
        bres_c[tid] = b2 + resb[tid];
    }
}

// ---- compose stage 2: Ws_c[r] = Wpn@Wsrc_r (+bias), VdstT = Wpn-projected a1 ----
__global__ __launch_bounds__(128) void k_compose2(
    const float* __restrict__ Wpn, const float* __restrict__ bpn,
    const float* __restrict__ Wsrc, const float* __restrict__ bsrc,
    const float* __restrict__ avec,
    float* __restrict__ Ws_c, float* __restrict__ bs_c,
    float* __restrict__ VdstT, float* __restrict__ cdst) {
    __shared__ float row[DD];
    const int rel = blockIdx.x, rrow = blockIdx.y, tid = threadIdx.x;
    row[tid] = Wpn[rrow * DD + tid];
    __syncthreads();
    const float* W = Wsrc + (size_t)rel * DD * DD;
    float acc = 0.f;
    for (int k = 0; k < DD; ++k) acc = fmaf(row[k], W[k * DD + tid], acc);
    Ws_c[(size_t)rel * DD * DD + rrow * DD + tid] = acc;
    if (tid < HH) {  // head = tid
        float v = 0.f;
        for (int d = 0; d < 16; ++d)
            v += row[tid * 16 + d] * avec[rel * 256 + tid * 32 + 16 + d];
        VdstT[(rel * HH + tid) * DD + rrow] = v;
    }
    if (rrow == 0) {
        float b = 0.f;
        for (int k = 0; k < DD; ++k) b = fmaf(bpn[k], W[k * DD + tid], b);
        bs_c[rel * DD + tid] = b + bsrc[rel * DD + tid];
        if (rel == 0 && tid < 16) {
            int r2 = tid >> 3, h2 = tid & 7;
            float c2 = 0.f;
            for (int d = 0; d < 16; ++d)
                c2 += bpn[h2 * 16 + d] * avec[r2 * 256 + h2 * 32 + 16 + d];
            cdst[tid] = c2;
        }
    }
}

// ---- main node GEMM: s0|s1|res = x @ [Ws0|Ws1|Wres] (+bias), sc_src epilogue ----
__global__ __launch_bounds__(128) void k_node2(
    const float* __restrict__ x,
    const float* __restrict__ Ws0, const float* __restrict__ Ws1,
    const float* __restrict__ Wres,
    const float* __restrict__ bs_c, const float* __restrict__ bres_c,
    const float* __restrict__ avec,
    float* __restrict__ s_out, float* __restrict__ res_out,
    float* __restrict__ sc_src) {
    __shared__ float xs[NB2][DD];
    const int tid = threadIdx.x;
    const int n0 = blockIdx.x * NB2;

    #pragma unroll
    for (int i = 0; i < NB2; ++i) xs[i][tid] = x[(size_t)(n0 + i) * DD + tid];
    __syncthreads();

    float a0[NB2], a1[NB2], a2[NB2];
    #pragma unroll
    for (int i = 0; i < NB2; ++i) { a0[i] = 0.f; a1[i] = 0.f; a2[i] = 0.f; }

    for (int k0 = 0; k0 < DD; k0 += 4) {
        float w0[4], w1[4], w2[4];
        #pragma unroll
        for (int kk = 0; kk < 4; ++kk) {
            w0[kk] = Ws0[(k0 + kk) * DD + tid];
            w1[kk] = Ws1[(k0 + kk) * DD + tid];
            w2[kk] = Wres[(k0 + kk) * DD + tid];
        }
        #pragma unroll
        for (int i = 0; i < NB2; ++i) {
            float4 xv = *(const float4*)&xs[i][k0];
            a0[i] = fmaf(xv.x, w0[0], a0[i]); a0[i] = fmaf(xv.y, w0[1], a0[i]);
            a0[i] = fmaf(xv.z, w0[2], a0[i]); a0[i] = fmaf(xv.w, w0[3], a0[i]);
            a1[i] = fmaf(xv.x, w1[0], a1[i]); a1[i] = fmaf(xv.y, w1[1], a1[i]);
            a1[i] = fmaf(xv.z, w1[2], a1[i]); a1[i] = fmaf(xv.w, w1[3], a1[i]);
            a2[i] = fmaf(xv.x, w2[0], a2[i]); a2[i] = fmaf(xv.y, w2[1], a2[i]);
            a2[i] = fmaf(xv.z, w2[2], a2[i]); a2[i] = fmaf(xv.w, w2[3], a2[i]);
        }
    }

    const int head = tid >> 4, d = tid & 15;
    #pragma unroll
    for (int r = 0; r < RR; ++r) {
        float av = avec[r * 256 + head * 32 + d];   // a[:,0]
        float bb = bs_c[r * DD + tid];
        #pragma unroll
        for (int i = 0; i < NB2; ++i) {
            float sv = (r == 0 ? a0[i] : a1[i]) + bb;
            s_out[(size_t)(r * NN + n0 + i) * DD + tid] = sv;
            float p = reduce16(sv * av);
            if (d == 0) sc_src[(size_t)(r * NN + n0 + i) * HH + head] = p;
        }
    }
    float br = bres_c[tid];
    #pragma unroll
    for (int i = 0; i < NB2; ++i)
        res_out[(size_t)(n0 + i) * DD + tid] = a2[i] + br;
}

// ---- sc_dst = x @ VdstT^T + cdst  (128x16 GEMM) ----
__global__ __launch_bounds__(256) void k_scdst(
    const float* __restrict__ x, const float* __restrict__ VdstT,
    const float* __restrict__ cdst, float* __restrict__ sc_dst) {
    __shared__ float xs[16][DD];
    const int tid = threadIdx.x;
    const int n0 = blockIdx.x * 16;
    for (int q = tid; q < 16 * DD; q += 256) xs[q >> 7][q & 127] = x[(size_t)n0 * DD + q];
    __syncthreads();
    const int nl = tid >> 4, c = tid & 15;
    float acc = cdst[c];
    const float* vrow = VdstT + c * DD;
    for (int k0 = 0; k0 < DD; k0 += 4) {
        float4 xv = *(const float4*)&xs[nl][k0];
        float4 vv = *(const float4*)&vrow[k0];
        acc = fmaf(xv.x, vv.x, acc); acc = fmaf(xv.y, vv.y, acc);
        acc = fmaf(xv.z, vv.z, acc); acc = fmaf(xv.w, vv.w, acc);
    }
    const int r = c >> 3, h = c & 7;
    sc_dst[((size_t)r * NN + n0 + nl) * HH + h] = acc;
}

// ---- CSR build ----
__global__ void k_zero(int* __restrict__ cnt) {
    int i = blockIdx.x * blockDim.x + threadIdx.x;
    if (i < RN) cnt[i] = 0;
}

__global__ void k_count(const int* __restrict__ dst, int* __restrict__ cnt) {
    int idx = blockIdx.x * blockDim.x + threadIdx.x;
    if (idx >= RR * EE) return;
    int r = idx / EE;
    atomicAdd(&cnt[r * NN + dst[idx]], 1);
}

__global__ __launch_bounds__(SCAN_CHUNK) void k_scan1(const int* __restrict__ cnt,
                                                      int* __restrict__ row_ptr,
                                                      int* __restrict__ blk) {
    __shared__ int sh[SCAN_CHUNK];
    const int tid = threadIdx.x;
    const int i = blockIdx.x * SCAN_CHUNK + tid;
    int v = (i < RN) ? cnt[i] : 0;
    sh[tid] = v;
    __syncthreads();
    for (int off = 1; off < SCAN_CHUNK; off <<= 1) {
        int t = (tid >= off) ? sh[tid - off] : 0;
        __syncthreads();
        sh[tid] += t;
        __syncthreads();
    }
    if (i < RN) row_ptr[i] = sh[tid] - v;
    if (tid == SCAN_CHUNK - 1) blk[blockIdx.x] = sh[tid];
}

__global__ __launch_bounds__(256) void k_scan2(int* __restrict__ blk) {
    __shared__ int sh[256];
    const int tid = threadIdx.x;
    int v = (tid < NBLK) ? blk[tid] : 0;
    sh[tid] = v;
    __syncthreads();
    for (int off = 1; off < 256; off <<= 1) {
        int t = (tid >= off) ? sh[tid - off] : 0;
        __syncthreads();
        sh[tid] += t;
        __syncthreads();
    }
    if (tid < NBLK) blk[tid] = sh[tid] - v;
}

__global__ void k_scan3(int* __restrict__ row_ptr, int* __restrict__ cursor,
                        const int* __restrict__ blk) {
    int i = blockIdx.x * blockDim.x + threadIdx.x;
    if (i < RN) {
        int v = row_ptr[i] + blk[i / SCAN_CHUNK];
        row_ptr[i] = v;
        cursor[i] = v;
    }
    if (i == 0) row_ptr[RN] = RR * EE;
}

__global__ void k_fill(const int* __restrict__ dst, int* __restrict__ cursor,
                       int* __restrict__ eid) {
    int idx = blockIdx.x * blockDim.x + threadIdx.x;
    if (idx >= RR * EE) return;
    int r = idx / EE;
    int e = idx - r * EE;
    int pos = atomicAdd(&cursor[r * NN + dst[idx]], 1);
    eid[pos] = e;
}

__global__ void k_sortseg(const int* __restrict__ row_ptr, int* __restrict__ eid) {
    int s = blockIdx.x * blockDim.x + threadIdx.x;
    if (s >= RN) return;
    int p0 = row_ptr[s], p1 = row_ptr[s + 1];
    for (int i = p0; i < p1 - 1; ++i) {
        int mn = eid[i], mi = i;
        for (int k = i + 1; k < p1; ++k) {
            int v = eid[k];
            if (v < mn) { mn = v; mi = k; }
        }
        eid[mi] = eid[i];
        eid[i] = mn;
    }
}

// ---- fused gather: segment softmax + message agg + gate + relation crossing ----
__global__ __launch_bounds__(256) void k_gather_cross(
    const int* __restrict__ src, const int* __restrict__ row_ptr,
    const int* __restrict__ eid,
    const float* __restrict__ sc_src, const float* __restrict__ sc_dst,
    const float* __restrict__ s, const float* __restrict__ res_buf,
    const float* __restrict__ res_alpha, const float* __restrict__ crossW,
    float* __restrict__ out) {
    int n = blockIdx.x * 4 + (threadIdx.x >> 6);
    if (n >= NN) return;
    const int lane = threadIdx.x & 63;
    const int g = lane >> 5;
    const int j = lane & 31;
    const int h = j >> 2;

    const int seg = g * NN + n;
    const int p0 = row_ptr[seg], p1 = row_ptr[seg + 1];
    const float sd = sc_dst[(size_t)seg * HH + h];

    float mx = -INFINITY;
    for (int p = p0; p < p1; ++p) {
        int sr = src[g * EE + eid[p]];
        float v = lrelu(sc_src[(size_t)(g * NN + sr) * HH + h] + sd);
        mx = fmaxf(mx, v);
    }
    float den = 0.f;
    float4 acc = {0.f, 0.f, 0.f, 0.f};
    for (int p = p0; p < p1; ++p) {
        int sr = src[g * EE + eid[p]];
        float v = lrelu(sc_src[(size_t)(g * NN + sr) * HH + h] + sd);
        float e = __expf(v - mx);
        den += e;
        float4 s4 = *(const float4*)(s + (size_t)(g * NN + sr) * DD + j * 4);
        acc.x = fmaf(e, s4.x, acc.x);
        acc.y = fmaf(e, s4.y, acc.y);
        acc.z = fmaf(e, s4.z, acc.z);
        acc.w = fmaf(e, s4.w, acc.w);
    }
    float inv = (p1 > p0) ? 1.f / den : 0.f;

    float gate = 1.f / (1.f + __expf(-res_alpha[0]));
    float4 r4 = *(const float4*)(res_buf + (size_t)n * DD + j * 4);
    float4 og;
    og.x = fmaf(acc.x * inv, gate, r4.x * (1.f - gate));
    og.y = fmaf(acc.y * inv, gate, r4.y * (1.f - gate));
    og.z = fmaf(acc.z * inv, gate, r4.z * (1.f - gate));
    og.w = fmaf(acc.w * inv, gate, r4.w * (1.f - gate));

    float4 oo;
    oo.x = __shfl_xor(og.x, 32);
    oo.y = __shfl_xor(og.y, 32);
    oo.z = __shfl_xor(og.z, 32);
    oo.w = __shfl_xor(og.w, 32);

    float4 cw = *(const float4*)(crossW + g * DD + j * 4);
    float ds_ = og.x * cw.x + og.y * cw.y + og.z * cw.z + og.w * cw.w;
    float do_ = oo.x * cw.x + oo.y * cw.y + oo.z * cw.z + oo.w * cw.w;
    ds_ += __shfl_xor(ds_, 1); ds_ += __shfl_xor(ds_, 2);
    do_ += __shfl_xor(do_, 1); do_ += __shfl_xor(do_, 2);
    float l0 = lrelu(ds_), l1 = lrelu(do_);
    float mm = fmaxf(l0, l1);
    float e0 = __expf(l0 - mm), e1 = __expf(l1 - mm);
    float winv = 1.f / (e0 + e1);
    float w0 = e0 * winv, w1 = e1 * winv;

    float4 o;
    o.x = w0 * og.x + w1 * oo.x;
    o.y = w0 * og.y + w1 * oo.y;
    o.z = w0 * og.z + w1 * oo.z;
    o.w = w0 * og.w + w1 * oo.w;
    *(float4*)(out + (size_t)(g * NN + n) * DD + j * 4) = o;
}

extern "C" void kernel_launch(void* const* d_in, const int* in_sizes, int n_in,
                              void* d_out, int out_size, void* d_ws, size_t ws_size,
                              hipStream_t stream) {
    const float* x        = (const float*)d_in[0];
    const int*   src      = (const int*)d_in[1];
    const int*   dst      = (const int*)d_in[2];
    const float* rel_emb  = (const float*)d_in[3];
    const float* Wp       = (const float*)d_in[4];
    const float* bp       = (const float*)d_in[5];
    const float* Wn       = (const float*)d_in[6];
    const float* bn       = (const float*)d_in[7];
    const float* Wsrc     = (const float*)d_in[8];
    const float* bsrc     = (const float*)d_in[9];
    const float* Wrel     = (const float*)d_in[10];
    const float* resW     = (const float*)d_in[11];
    const float* resb     = (const float*)d_in[12];
    const float* res_alpha= (const float*)d_in[13];
    const float* crossW   = (const float*)d_in[14];
    const float* Wprop    = (const float*)d_in[15];
    const float* bprop    = (const float*)d_in[16];

    float* out = (float*)d_out;
    float* ws  = (float*)d_ws;

    // workspace layout (floats)
    float* s_buf   = ws;                                  // R*N*D
    float* res_buf = s_buf   + (size_t)RR * NN * DD;      // N*D
    float* sc_src  = res_buf + (size_t)NN * DD;           // R*N*H
    float* sc_dst  = sc_src  + (size_t)RR * NN * HH;      // R*N*H
    float* avec    = sc_dst  + (size_t)RR * NN * HH;      // 512
    float* Wpn     = avec    + 512;                       // 16384
    float* Wres_c  = Wpn     + DD * DD;                   // 16384
    float* Ws_c    = Wres_c  + DD * DD;                   // 2*16384
    float* VdstT   = Ws_c    + (size_t)RR * DD * DD;      // 16*128
    float* bpn     = VdstT   + 16 * DD;                   // 128
    float* bres_c  = bpn     + DD;                        // 128
    float* bs_c    = bres_c  + DD;                        // 256
    float* cdst    = bs_c    + RR * DD;                   // 16
    int*   cnt     = (int*)(cdst + 16);                   // RN
    int*   row_ptr = cnt + RN;                            // RN + 1
    int*   cursor  = row_ptr + RN + 1;                    // RN
    int*   eid     = cursor + RN;                         // R*E
    int*   blk     = eid + RR * EE;                       // NBLK

    k_prep<<<1, 256, 0, stream>>>(rel_emb, Wrel, Wprop, bprop, avec,
                                  out + (size_t)RR * NN * DD);
    k_compose1<<<DD, DD, 0, stream>>>(Wp, bp, Wn, bn, resW, resb,
                                      Wpn, bpn, Wres_c, bres_c);
    k_compose2<<<dim3(RR, DD), DD, 0, stream>>>(Wpn, bpn, Wsrc, bsrc, avec,
                                                Ws_c, bs_c, VdstT, cdst);
    k_node2<<<NN / NB2, 128, 0, stream>>>(x, Ws_c, Ws_c + (size_t)DD * DD, Wres_c,
                                          bs_c, bres_c, avec,
                                          s_buf, res_buf, sc_src);
    k_scdst<<<NN / 16, 256, 0, stream>>>(x, VdstT, cdst, sc_dst);
    k_zero<<<(RN + 255) / 256, 256, 0, stream>>>(cnt);
    k_count<<<(RR * EE + 255) / 256, 256, 0, stream>>>(dst, cnt);
    k_scan1<<<NBLK, SCAN_CHUNK, 0, stream>>>(cnt, row_ptr, blk);
    k_scan2<<<1, 256, 0, stream>>>(blk);
    k_scan3<<<(RN + 255) / 256, 256, 0, stream>>>(row_ptr, cursor, blk);
    k_fill<<<(RR * EE + 255) / 256, 256, 0, stream>>>(dst, cursor, eid);
    k_sortseg<<<(RN + 255) / 256, 256, 0, stream>>>(row_ptr, eid);
    k_gather_cross<<<(NN + 3) / 4, 256, 0, stream>>>(src, row_ptr, eid, sc_src, sc_dst,
                                                     s_buf, res_buf, res_alpha, crossW,
                                                     out);
}

// Round 5
// 682.752 us; speedup vs baseline: 4.9110x; 1.0224x over previous
//
#include <hip/hip_runtime.h>
#include <math.h>

#define NN 100000
#define EE 600000
#define RR 2
#define DD 128
#define HH 8
#define DHH 16
#define RN (RR * NN)
#define NB2 16   // nodes per block in node GEMM
#define SCAN_CHUNK 1024
#define NBLK ((RN + SCAN_CHUNK - 1) / SCAN_CHUNK)   // 196

typedef unsigned short ushort_t;

__device__ __forceinline__ float lrelu(float v) { return v >= 0.f ? v : 0.2f * v; }

__device__ __forceinline__ float reduce16(float p) {
    p += __shfl_xor(p, 1);
    p += __shfl_xor(p, 2);
    p += __shfl_xor(p, 4);
    p += __shfl_xor(p, 8);
    return p;
}

// f32 -> bf16 (round to nearest even), bf16 -> f32 (exact)
__device__ __forceinline__ ushort_t f2bf(float f) {
    unsigned int u = __float_as_uint(f);
    u = (u + 0x7FFFu + ((u >> 16) & 1u)) >> 16;
    return (ushort_t)u;
}
__device__ __forceinline__ float bf2f(ushort_t u) {
    return __uint_as_float(((unsigned int)u) << 16);
}

// ---- prep: a = rel_emb @ Wrel  [R*256], rel_out = rel_emb @ Wprop + bprop ----
__global__ void k_prep(const float* __restrict__ rel_emb, const float* __restrict__ Wrel,
                       const float* __restrict__ Wprop, const float* __restrict__ bprop,
                       float* __restrict__ avec, float* __restrict__ rel_out) {
    int tid = threadIdx.x;
    for (int idx = tid; idx < RR * 256; idx += 256) {
        int r = idx >> 8, o = idx & 255;
        float acc = 0.f;
        for (int i = 0; i < 64; ++i)
            acc += rel_emb[r * 64 + i] * Wrel[(r * 64 + i) * 256 + o];
        avec[idx] = acc;
    }
    {   // rel_out: 256 outputs, one per thread
        int r = tid >> 7, o = tid & 127;
        float acc = bprop[tid];
        for (int i = 0; i < 64; ++i)
            acc += rel_emb[r * 64 + i] * Wprop[(r * 64 + i) * 128 + o];
        rel_out[tid] = acc;
    }
}

// ---- compose stage 1: Wpn = Wp@Wn, Wres_c = Wp@resW (+ bias folds) ----
__global__ __launch_bounds__(128) void k_compose1(
    const float* __restrict__ Wp, const float* __restrict__ bp,
    const float* __restrict__ Wn, const float* __restrict__ bn,
    const float* __restrict__ resW, const float* __restrict__ resb,
    float* __restrict__ Wpn, float* __restrict__ bpn,
    float* __restrict__ Wres_c, float* __restrict__ bres_c) {
    __shared__ float row[DD];
    const int rrow = blockIdx.x, tid = threadIdx.x;
    row[tid] = Wp[rrow * DD + tid];
    __syncthreads();
    float acc1 = 0.f, acc2 = 0.f;
    for (int k = 0; k < DD; ++k) {
        float wv = row[k];
        acc1 = fmaf(wv, Wn[k * DD + tid], acc1);
        acc2 = fmaf(wv, resW[k * DD + tid], acc2);
    }
    Wpn[rrow * DD + tid] = acc1;
    Wres_c[rrow * DD + tid] = acc2;
    if (rrow == 0) {
        float b1 = 0.f, b2 = 0.f;
        for (int k = 0; k < DD; ++k) {
            b1 = fmaf(bp[k], Wn[k * DD + tid], b1);
            b2 = fmaf(bp[k], resW[k * DD + tid], b2);
        }
        bpn[tid] = b1 + bn[tid];
        bres_c[tid] = b2 + resb[tid];
    }
}

// ---- compose stage 2: Ws_c[r] = Wpn@Wsrc_r (+bias), VdstT = Wpn-projected a1 ----
__global__ __launch_bounds__(128) void k_compose2(
    const float* __restrict__ Wpn, const float* __restrict__ bpn,
    const float* __restrict__ Wsrc, const float* __restrict__ bsrc,
    const float* __restrict__ avec,
    float* __restrict__ Ws_c, float* __restrict__ bs_c,
    float* __restrict__ VdstT, float* __restrict__ cdst) {
    __shared__ float row[DD];
    const int rel = blockIdx.x, rrow = blockIdx.y, tid = threadIdx.x;
    row[tid] = Wpn[rrow * DD + tid];
    __syncthreads();
    const float* W = Wsrc + (size_t)rel * DD * DD;
    float acc = 0.f;
    for (int k = 0; k < DD; ++k) acc = fmaf(row[k], W[k * DD + tid], acc);
    Ws_c[(size_t)rel * DD * DD + rrow * DD + tid] = acc;
    if (tid < HH) {  // head = tid
        float v = 0.f;
        for (int d = 0; d < 16; ++d)
            v += row[tid * 16 + d] * avec[rel * 256 + tid * 32 + 16 + d];
        VdstT[(rel * HH + tid) * DD + rrow] = v;
    }
    if (rrow == 0) {
        float b = 0.f;
        for (int k = 0; k < DD; ++k) b = fmaf(bpn[k], W[k * DD + tid], b);
        bs_c[rel * DD + tid] = b + bsrc[rel * DD + tid];
        if (rel == 0 && tid < 16) {
            int r2 = tid >> 3, h2 = tid & 7;
            float c2 = 0.f;
            for (int d = 0; d < 16; ++d)
                c2 += bpn[h2 * 16 + d] * avec[r2 * 256 + h2 * 32 + 16 + d];
            cdst[tid] = c2;
        }
    }
}

// ---- main node GEMM: s0|s1|res = x @ [Ws0|Ws1|Wres] (+bias); epilogues:
//      sc_src (per-head dot), bf16 stores, and folded sc_dst = x @ VdstT^T ----
__global__ __launch_bounds__(128) void k_node2(
    const float* __restrict__ x,
    const float* __restrict__ Ws0, const float* __restrict__ Ws1,
    const float* __restrict__ Wres,
    const float* __restrict__ bs_c, const float* __restrict__ bres_c,
    const float* __restrict__ avec,
    const float* __restrict__ VdstT, const float* __restrict__ cdst,
    ushort_t* __restrict__ s_out, ushort_t* __restrict__ res_out,
    float* __restrict__ sc_src, float* __restrict__ sc_dst) {
    __shared__ float xs[NB2][DD];
    const int tid = threadIdx.x;
    const int n0 = blockIdx.x * NB2;

    #pragma unroll
    for (int i = 0; i < NB2; ++i) xs[i][tid] = x[(size_t)(n0 + i) * DD + tid];
    __syncthreads();

    float a0[NB2], a1[NB2], a2[NB2];
    #pragma unroll
    for (int i = 0; i < NB2; ++i) { a0[i] = 0.f; a1[i] = 0.f; a2[i] = 0.f; }

    for (int k0 = 0; k0 < DD; k0 += 4) {
        float w0[4], w1[4], w2[4];
        #pragma unroll
        for (int kk = 0; kk < 4; ++kk) {
            w0[kk] = Ws0[(k0 + kk) * DD + tid];
            w1[kk] = Ws1[(k0 + kk) * DD + tid];
            w2[kk] = Wres[(k0 + kk) * DD + tid];
        }
        #pragma unroll
        for (int i = 0; i < NB2; ++i) {
            float4 xv = *(const float4*)&xs[i][k0];
            a0[i] = fmaf(xv.x, w0[0], a0[i]); a0[i] = fmaf(xv.y, w0[1], a0[i]);
            a0[i] = fmaf(xv.z, w0[2], a0[i]); a0[i] = fmaf(xv.w, w0[3], a0[i]);
            a1[i] = fmaf(xv.x, w1[0], a1[i]); a1[i] = fmaf(xv.y, w1[1], a1[i]);
            a1[i] = fmaf(xv.z, w1[2], a1[i]); a1[i] = fmaf(xv.w, w1[3], a1[i]);
            a2[i] = fmaf(xv.x, w2[0], a2[i]); a2[i] = fmaf(xv.y, w2[1], a2[i]);
            a2[i] = fmaf(xv.z, w2[2], a2[i]); a2[i] = fmaf(xv.w, w2[3], a2[i]);
        }
    }

    const int head = tid >> 4, d = tid & 15;
    #pragma unroll
    for (int r = 0; r < RR; ++r) {
        float av = avec[r * 256 + head * 32 + d];   // a[:,0]
        float bb = bs_c[r * DD + tid];
        #pragma unroll
        for (int i = 0; i < NB2; ++i) {
            float sv = (r == 0 ? a0[i] : a1[i]) + bb;
            s_out[(size_t)(r * NN + n0 + i) * DD + tid] = f2bf(sv);
            float p = reduce16(sv * av);
            if (d == 0) sc_src[(size_t)(r * NN + n0 + i) * HH + head] = p;
        }
    }
    float br = bres_c[tid];
    #pragma unroll
    for (int i = 0; i < NB2; ++i)
        res_out[(size_t)(n0 + i) * DD + tid] = f2bf(a2[i] + br);

    // folded sc_dst: c = rel*8 + head (16 cols), 8 node-slots per pass
    const int c = tid & 15;
    const int slot = tid >> 4;   // 0..7
    const float* vrow = VdstT + c * DD;
    #pragma unroll
    for (int it = 0; it < NB2 / 8; ++it) {
        int node = slot + it * 8;
        float acc = cdst[c];
        for (int k0 = 0; k0 < DD; k0 += 4) {
            float4 xv = *(const float4*)&xs[node][k0];
            float4 vv = *(const float4*)&vrow[k0];
            acc = fmaf(xv.x, vv.x, acc); acc = fmaf(xv.y, vv.y, acc);
            acc = fmaf(xv.z, vv.z, acc); acc = fmaf(xv.w, vv.w, acc);
        }
        sc_dst[((size_t)(c >> 3) * NN + n0 + node) * HH + (c & 7)] = acc;
    }
}

// ---- CSR build ----
__global__ void k_zero(int* __restrict__ cnt) {
    int i = blockIdx.x * blockDim.x + threadIdx.x;
    if (i < RN) cnt[i] = 0;
}

__global__ void k_count(const int* __restrict__ dst, int* __restrict__ cnt) {
    int idx = blockIdx.x * blockDim.x + threadIdx.x;
    if (idx >= RR * EE) return;
    int r = idx / EE;
    atomicAdd(&cnt[r * NN + dst[idx]], 1);
}

__global__ __launch_bounds__(SCAN_CHUNK) void k_scan1(const int* __restrict__ cnt,
                                                      int* __restrict__ row_ptr,
                                                      int* __restrict__ blk) {
    __shared__ int sh[SCAN_CHUNK];
    const int tid = threadIdx.x;
    const int i = blockIdx.x * SCAN_CHUNK + tid;
    int v = (i < RN) ? cnt[i] : 0;
    sh[tid] = v;
    __syncthreads();
    for (int off = 1; off < SCAN_CHUNK; off <<= 1) {
        int t = (tid >= off) ? sh[tid - off] : 0;
        __syncthreads();
        sh[tid] += t;
        __syncthreads();
    }
    if (i < RN) row_ptr[i] = sh[tid] - v;
    if (tid == SCAN_CHUNK - 1) blk[blockIdx.x] = sh[tid];
}

__global__ __launch_bounds__(256) void k_scan2(int* __restrict__ blk) {
    __shared__ int sh[256];
    const int tid = threadIdx.x;
    int v = (tid < NBLK) ? blk[tid] : 0;
    sh[tid] = v;
    __syncthreads();
    for (int off = 1; off < 256; off <<= 1) {
        int t = (tid >= off) ? sh[tid - off] : 0;
        __syncthreads();
        sh[tid] += t;
        __syncthreads();
    }
    if (tid < NBLK) blk[tid] = sh[tid] - v;
}

__global__ void k_scan3(int* __restrict__ row_ptr, int* __restrict__ cursor,
                        const int* __restrict__ blk) {
    int i = blockIdx.x * blockDim.x + threadIdx.x;
    if (i < RN) {
        int v = row_ptr[i] + blk[i / SCAN_CHUNK];
        row_ptr[i] = v;
        cursor[i] = v;
    }
    if (i == 0) row_ptr[RN] = RR * EE;
}

__global__ void k_fill(const int* __restrict__ dst, int* __restrict__ cursor,
                       int* __restrict__ eid) {
    int idx = blockIdx.x * blockDim.x + threadIdx.x;
    if (idx >= RR * EE) return;
    int r = idx / EE;
    int e = idx - r * EE;
    int pos = atomicAdd(&cursor[r * NN + dst[idx]], 1);
    eid[pos] = e;
}

__global__ void k_sortseg(const int* __restrict__ row_ptr, int* __restrict__ eid) {
    int s = blockIdx.x * blockDim.x + threadIdx.x;
    if (s >= RN) return;
    int p0 = row_ptr[s], p1 = row_ptr[s + 1];
    for (int i = p0; i < p1 - 1; ++i) {
        int mn = eid[i], mi = i;
        for (int k = i + 1; k < p1; ++k) {
            int v = eid[k];
            if (v < mn) { mn = v; mi = k; }
        }
        eid[mi] = eid[i];
        eid[i] = mn;
    }
}

// ---- fused gather: online segment softmax + message agg + gate + crossing ----
// One wave64 per node: lanes 0-31 -> relation 0, lanes 32-63 -> relation 1.
// Lane j (0..31) within group handles columns 4j..4j+3 (head h = j>>2).
__global__ __launch_bounds__(256) void k_gather_cross(
    const int* __restrict__ src, const int* __restrict__ row_ptr,
    const int* __restrict__ eid,
    const float* __restrict__ sc_src, const float* __restrict__ sc_dst,
    const ushort_t* __restrict__ s, const ushort_t* __restrict__ res_buf,
    const float* __restrict__ res_alpha, const float* __restrict__ crossW,
    float* __restrict__ out) {
    int n = blockIdx.x * 4 + (threadIdx.x >> 6);
    if (n >= NN) return;
    const int lane = threadIdx.x & 63;
    const int g = lane >> 5;
    const int j = lane & 31;
    const int h = j >> 2;

    const int seg = g * NN + n;
    const int p0 = row_ptr[seg], p1 = row_ptr[seg + 1];
    const float sd = sc_dst[(size_t)seg * HH + h];

    // single pass: online softmax + weighted accumulate (bf16 payload)
    float mx = -INFINITY, den = 0.f;
    float4 acc = {0.f, 0.f, 0.f, 0.f};
    for (int p = p0; p < p1; ++p) {
        int sr = src[g * EE + eid[p]];
        float v = lrelu(sc_src[(size_t)(g * NN + sr) * HH + h] + sd);
        float e;
        if (v > mx) {
            float sc = __expf(mx - v);   // first iter: exp(-inf) = 0
            den *= sc;
            acc.x *= sc; acc.y *= sc; acc.z *= sc; acc.w *= sc;
            mx = v;
            e = 1.f;
        } else {
            e = __expf(v - mx);
        }
        den += e;
        ushort4 s4 = *(const ushort4*)(s + (size_t)(g * NN + sr) * DD + j * 4);
        acc.x = fmaf(e, bf2f(s4.x), acc.x);
        acc.y = fmaf(e, bf2f(s4.y), acc.y);
        acc.z = fmaf(e, bf2f(s4.z), acc.z);
        acc.w = fmaf(e, bf2f(s4.w), acc.w);
    }
    float inv = (p1 > p0) ? 1.f / den : 0.f;

    float gate = 1.f / (1.f + __expf(-res_alpha[0]));
    ushort4 r4u = *(const ushort4*)(res_buf + (size_t)n * DD + j * 4);
    float4 og;
    og.x = fmaf(acc.x * inv, gate, bf2f(r4u.x) * (1.f - gate));
    og.y = fmaf(acc.y * inv, gate, bf2f(r4u.y) * (1.f - gate));
    og.z = fmaf(acc.z * inv, gate, bf2f(r4u.z) * (1.f - gate));
    og.w = fmaf(acc.w * inv, gate, bf2f(r4u.w) * (1.f - gate));

    float4 oo;
    oo.x = __shfl_xor(og.x, 32);
    oo.y = __shfl_xor(og.y, 32);
    oo.z = __shfl_xor(og.z, 32);
    oo.w = __shfl_xor(og.w, 32);

    float4 cw = *(const float4*)(crossW + g * DD + j * 4);
    float ds_ = og.x * cw.x + og.y * cw.y + og.z * cw.z + og.w * cw.w;
    float do_ = oo.x * cw.x + oo.y * cw.y + oo.z * cw.z + oo.w * cw.w;
    ds_ += __shfl_xor(ds_, 1); ds_ += __shfl_xor(ds_, 2);
    do_ += __shfl_xor(do_, 1); do_ += __shfl_xor(do_, 2);
    float l0 = lrelu(ds_), l1 = lrelu(do_);
    float mm = fmaxf(l0, l1);
    float e0 = __expf(l0 - mm), e1 = __expf(l1 - mm);
    float winv = 1.f / (e0 + e1);
    float w0 = e0 * winv, w1 = e1 * winv;

    float4 o;
    o.x = w0 * og.x + w1 * oo.x;
    o.y = w0 * og.y + w1 * oo.y;
    o.z = w0 * og.z + w1 * oo.z;
    o.w = w0 * og.w + w1 * oo.w;
    *(float4*)(out + (size_t)(g * NN + n) * DD + j * 4) = o;
}

extern "C" void kernel_launch(void* const* d_in, const int* in_sizes, int n_in,
                              void* d_out, int out_size, void* d_ws, size_t ws_size,
                              hipStream_t stream) {
    const float* x        = (const float*)d_in[0];
    const int*   src      = (const int*)d_in[1];
    const int*   dst      = (const int*)d_in[2];
    const float* rel_emb  = (const float*)d_in[3];
    const float* Wp       = (const float*)d_in[4];
    const float* bp       = (const float*)d_in[5];
    const float* Wn       = (const float*)d_in[6];
    const float* bn       = (const float*)d_in[7];
    const float* Wsrc     = (const float*)d_in[8];
    const float* bsrc     = (const float*)d_in[9];
    const float* Wrel     = (const float*)d_in[10];
    const float* resW     = (const float*)d_in[11];
    const float* resb     = (const float*)d_in[12];
    const float* res_alpha= (const float*)d_in[13];
    const float* crossW   = (const float*)d_in[14];
    const float* Wprop    = (const float*)d_in[15];
    const float* bprop    = (const float*)d_in[16];

    float* out = (float*)d_out;

    // workspace layout: bf16 buffers first (large, aligned), then f32, then ints
    ushort_t* s_bf   = (ushort_t*)d_ws;                    // R*N*D ushorts
    ushort_t* res_bf = s_bf + (size_t)RR * NN * DD;        // N*D ushorts
    float* fbase   = (float*)(res_bf + (size_t)NN * DD);
    float* sc_src  = fbase;                                // R*N*H
    float* sc_dst  = sc_src  + (size_t)RR * NN * HH;       // R*N*H
    float* avec    = sc_dst  + (size_t)RR * NN * HH;       // 512
    float* Wpn     = avec    + 512;                        // 16384
    float* Wres_c  = Wpn     + DD * DD;                    // 16384
    float* Ws_c    = Wres_c  + DD * DD;                    // 2*16384
    float* VdstT   = Ws_c    + (size_t)RR * DD * DD;       // 16*128
    float* bpn     = VdstT   + 16 * DD;                    // 128
    float* bres_c  = bpn     + DD;                         // 128
    float* bs_c    = bres_c  + DD;                         // 256
    float* cdst    = bs_c    + RR * DD;                    // 16
    int*   cnt     = (int*)(cdst + 16);                    // RN
    int*   row_ptr = cnt + RN;                             // RN + 1
    int*   cursor  = row_ptr + RN + 1;                     // RN
    int*   eid     = cursor + RN;                          // R*E
    int*   blk     = eid + RR * EE;                        // NBLK

    k_prep<<<1, 256, 0, stream>>>(rel_emb, Wrel, Wprop, bprop, avec,
                                  out + (size_t)RR * NN * DD);
    k_compose1<<<DD, DD, 0, stream>>>(Wp, bp, Wn, bn, resW, resb,
                                      Wpn, bpn, Wres_c, bres_c);
    k_compose2<<<dim3(RR, DD), DD, 0, stream>>>(Wpn, bpn, Wsrc, bsrc, avec,
                                                Ws_c, bs_c, VdstT, cdst);
    k_node2<<<NN / NB2, 128, 0, stream>>>(x, Ws_c, Ws_c + (size_t)DD * DD, Wres_c,
                                          bs_c, bres_c, avec, VdstT, cdst,
                                          s_bf, res_bf, sc_src, sc_dst);
    k_zero<<<(RN + 255) / 256, 256, 0, stream>>>(cnt);
    k_count<<<(RR * EE + 255) / 256, 256, 0, stream>>>(dst, cnt);
    k_scan1<<<NBLK, SCAN_CHUNK, 0, stream>>>(cnt, row_ptr, blk);
    k_scan2<<<1, 256, 0, stream>>>(blk);
    k_scan3<<<(RN + 255) / 256, 256, 0, stream>>>(row_ptr, cursor, blk);
    k_fill<<<(RR * EE + 255) / 256, 256, 0, stream>>>(dst, cursor, eid);
    k_sortseg<<<(RN + 255) / 256, 256, 0, stream>>>(row_ptr, eid);
    k_gather_cross<<<(NN + 3) / 4, 256, 0, stream>>>(src, row_ptr, eid, sc_src, sc_dst,
                                                     s_bf, res_bf, res_alpha, crossW,
                                                     out);
}

// Round 6
// 432.499 us; speedup vs baseline: 7.7525x; 1.5786x over previous
//
#include <hip/hip_runtime.h>
#include <math.h>

#define NN 100000
#define EE 600000
#define RR 2
#define DD 128
#define HH 8
#define DHH 16
#define RN (RR * NN)
#define SCAN_CHUNK 1024
#define NBLK ((RN + SCAN_CHUNK - 1) / SCAN_CHUNK)   // 196
#define NT 25   // N-tiles in node GEMM: 8 (s0) + 8 (s1) + 8 (res) + 1 (sc_dst)

typedef unsigned short ushort_t;
typedef short bf16x8 __attribute__((ext_vector_type(8)));
typedef float f32x4 __attribute__((ext_vector_type(4)));

__device__ __forceinline__ float lrelu(float v) { return v >= 0.f ? v : 0.2f * v; }

__device__ __forceinline__ float reduce16(float p) {
    p += __shfl_xor(p, 1);
    p += __shfl_xor(p, 2);
    p += __shfl_xor(p, 4);
    p += __shfl_xor(p, 8);
    return p;
}

// f32 -> bf16 (round to nearest even), bf16 -> f32 (exact)
__device__ __forceinline__ ushort_t f2bf(float f) {
    unsigned int u = __float_as_uint(f);
    u = (u + 0x7FFFu + ((u >> 16) & 1u)) >> 16;
    return (ushort_t)u;
}
__device__ __forceinline__ float bf2f(ushort_t u) {
    return __uint_as_float(((unsigned int)u) << 16);
}

// ---- prep: a = rel_emb @ Wrel  [R*256], rel_out = rel_emb @ Wprop + bprop ----
__global__ void k_prep(const float* __restrict__ rel_emb, const float* __restrict__ Wrel,
                       const float* __restrict__ Wprop, const float* __restrict__ bprop,
                       float* __restrict__ avec, float* __restrict__ rel_out) {
    int tid = threadIdx.x;
    for (int idx = tid; idx < RR * 256; idx += 256) {
        int r = idx >> 8, o = idx & 255;
        float acc = 0.f;
        for (int i = 0; i < 64; ++i)
            acc += rel_emb[r * 64 + i] * Wrel[(r * 64 + i) * 256 + o];
        avec[idx] = acc;
    }
    {   // rel_out: 256 outputs, one per thread
        int r = tid >> 7, o = tid & 127;
        float acc = bprop[tid];
        for (int i = 0; i < 64; ++i)
            acc += rel_emb[r * 64 + i] * Wprop[(r * 64 + i) * 128 + o];
        rel_out[tid] = acc;
    }
}

// ---- compose stage 1: Wpn = Wp@Wn, Wres_c = Wp@resW (+ bias folds) ----
__global__ __launch_bounds__(128) void k_compose1(
    const float* __restrict__ Wp, const float* __restrict__ bp,
    const float* __restrict__ Wn, const float* __restrict__ bn,
    const float* __restrict__ resW, const float* __restrict__ resb,
    float* __restrict__ Wpn, float* __restrict__ bpn,
    float* __restrict__ Wres_c, float* __restrict__ bres_c) {
    __shared__ float row[DD];
    const int rrow = blockIdx.x, tid = threadIdx.x;
    row[tid] = Wp[rrow * DD + tid];
    __syncthreads();
    float acc1 = 0.f, acc2 = 0.f;
    for (int k = 0; k < DD; ++k) {
        float wv = row[k];
        acc1 = fmaf(wv, Wn[k * DD + tid], acc1);
        acc2 = fmaf(wv, resW[k * DD + tid], acc2);
    }
    Wpn[rrow * DD + tid] = acc1;
    Wres_c[rrow * DD + tid] = acc2;
    if (rrow == 0) {
        float b1 = 0.f, b2 = 0.f;
        for (int k = 0; k < DD; ++k) {
            b1 = fmaf(bp[k], Wn[k * DD + tid], b1);
            b2 = fmaf(bp[k], resW[k * DD + tid], b2);
        }
        bpn[tid] = b1 + bn[tid];
        bres_c[tid] = b2 + resb[tid];
    }
}

// ---- compose stage 2: Ws_c[r] = Wpn@Wsrc_r (+bias), VdstT = Wpn-projected a1 ----
__global__ __launch_bounds__(128) void k_compose2(
    const float* __restrict__ Wpn, const float* __restrict__ bpn,
    const float* __restrict__ Wsrc, const float* __restrict__ bsrc,
    const float* __restrict__ avec,
    float* __restrict__ Ws_c, float* __restrict__ bs_c,
    float* __restrict__ VdstT, float* __restrict__ cdst) {
    __shared__ float row[DD];
    const int rel = blockIdx.x, rrow = blockIdx.y, tid = threadIdx.x;
    row[tid] = Wpn[rrow * DD + tid];
    __syncthreads();
    const float* W = Wsrc + (size_t)rel * DD * DD;
    float acc = 0.f;
    for (int k = 0; k < DD; ++k) acc = fmaf(row[k], W[k * DD + tid], acc);
    Ws_c[(size_t)rel * DD * DD + rrow * DD + tid] = acc;
    if (tid < HH) {  // head = tid
        float v = 0.f;
        for (int d = 0; d < 16; ++d)
            v += row[tid * 16 + d] * avec[rel * 256 + tid * 32 + 16 + d];
        VdstT[(rel * HH + tid) * DD + rrow] = v;
    }
    if (rrow == 0) {
        float b = 0.f;
        for (int k = 0; k < DD; ++k) b = fmaf(bpn[k], W[k * DD + tid], b);
        bs_c[rel * DD + tid] = b + bsrc[rel * DD + tid];
        if (rel == 0 && tid < 16) {
            int r2 = tid >> 3, h2 = tid & 7;
            float c2 = 0.f;
            for (int d = 0; d < 16; ++d)
                c2 += bpn[h2 * 16 + d] * avec[r2 * 256 + h2 * 32 + 16 + d];
            cdst[tid] = c2;
        }
    }
}

// ---- pack composed weights into MFMA B-fragment layout (bf16) ----
// Wcat cols: [0,128)=Ws0, [128,256)=Ws1, [256,384)=Wres, [384,400)=VdstT rows.
// B-frag for 16x16x32: lane l holds B[k=(l>>4)*8+j][col=l&15], j=0..7.
// Layout: Wpk[((t*4 + kt)*64 + l)*8 + j]
__global__ __launch_bounds__(256) void k_pack(
    const float* __restrict__ Ws_c, const float* __restrict__ Wres_c,
    const float* __restrict__ VdstT, short* __restrict__ Wpk) {
    const int t = blockIdx.x;
    const int kt = threadIdx.x >> 6;
    const int l = threadIdx.x & 63;
    const int c16 = l & 15;
    bf16x8 v;
    #pragma unroll
    for (int j = 0; j < 8; ++j) {
        int k = kt * 32 + (l >> 4) * 8 + j;
        float f;
        if (t < 24) {
            int m = t >> 3;                    // 0=Ws0, 1=Ws1, 2=Wres
            int col = (t & 7) * 16 + c16;
            const float* W = (m == 0) ? Ws_c : (m == 1) ? Ws_c + DD * DD : Wres_c;
            f = W[k * DD + col];
        } else {
            f = VdstT[c16 * DD + k];
        }
        v[j] = (short)f2bf(f);
    }
    *(bf16x8*)(Wpk + ((size_t)(t * 4 + kt) * 64 + l) * 8) = v;
}

// ---- node GEMM via MFMA: [32 nodes/block] x @ [Ws0|Ws1|Wres|Vdst] ----
// 2 waves/block, each wave 16 nodes. A-frag: lane l row=l&15, k=(l>>4)*8+j.
// D: col=l&15, row=(l>>4)*4+r.
__global__ __launch_bounds__(128) void k_node3(
    const float* __restrict__ x, const short* __restrict__ Wpk,
    const float* __restrict__ bs_c, const float* __restrict__ bres_c,
    const float* __restrict__ avec, const float* __restrict__ cdst,
    ushort_t* __restrict__ s_out, ushort_t* __restrict__ res_out,
    float* __restrict__ sc_src, float* __restrict__ sc_dst) {
    const int tid = threadIdx.x;
    const int l = tid & 63;
    const int w = tid >> 6;
    const int m16 = l & 15, g4 = l >> 4;
    const int nw0 = blockIdx.x * 32 + w * 16;

    // A fragments: 4 k-tiles, 8 bf16 each
    bf16x8 af[4];
    const float* xrow = x + (size_t)(nw0 + m16) * DD + g4 * 8;
    #pragma unroll
    for (int kt = 0; kt < 4; ++kt) {
        float4 v0 = *(const float4*)(xrow + kt * 32);
        float4 v1 = *(const float4*)(xrow + kt * 32 + 4);
        af[kt][0] = (short)f2bf(v0.x); af[kt][1] = (short)f2bf(v0.y);
        af[kt][2] = (short)f2bf(v0.z); af[kt][3] = (short)f2bf(v0.w);
        af[kt][4] = (short)f2bf(v1.x); af[kt][5] = (short)f2bf(v1.y);
        af[kt][6] = (short)f2bf(v1.z); af[kt][7] = (short)f2bf(v1.w);
    }

    for (int t = 0; t < NT; ++t) {
        f32x4 acc = {0.f, 0.f, 0.f, 0.f};
        #pragma unroll
        for (int kt = 0; kt < 4; ++kt) {
            bf16x8 b = *(const bf16x8*)(Wpk + ((size_t)(t * 4 + kt) * 64 + l) * 8);
            acc = __builtin_amdgcn_mfma_f32_16x16x32_bf16(af[kt], b, acc, 0, 0, 0);
        }
        if (t < 16) {
            const int rel = t >> 3, head = t & 7;
            const float a0v = avec[rel * 256 + head * 32 + m16];
            const float bb = bs_c[rel * DD + head * 16 + m16];
            #pragma unroll
            for (int r = 0; r < 4; ++r) {
                const int node = nw0 + g4 * 4 + r;
                float sv = acc[r] + bb;
                s_out[((size_t)rel * NN + node) * DD + head * 16 + m16] = f2bf(sv);
                float p = reduce16(sv * a0v);
                if (m16 == 0) sc_src[((size_t)rel * NN + node) * HH + head] = p;
            }
        } else if (t < 24) {
            const int col = (t - 16) * 16 + m16;
            const float bb = bres_c[col];
            #pragma unroll
            for (int r = 0; r < 4; ++r) {
                const int node = nw0 + g4 * 4 + r;
                res_out[(size_t)node * DD + col] = f2bf(acc[r] + bb);
            }
        } else {
            const int rel = m16 >> 3, head = m16 & 7;
            const float bb = cdst[m16];
            #pragma unroll
            for (int r = 0; r < 4; ++r) {
                const int node = nw0 + g4 * 4 + r;
                sc_dst[((size_t)rel * NN + node) * HH + head] = acc[r] + bb;
            }
        }
    }
}

// ---- CSR build ----
__global__ void k_zero(int* __restrict__ cnt) {
    int i = blockIdx.x * blockDim.x + threadIdx.x;
    if (i < RN) cnt[i] = 0;
}

__global__ void k_count(const int* __restrict__ dst, int* __restrict__ cnt) {
    int idx = blockIdx.x * blockDim.x + threadIdx.x;
    if (idx >= RR * EE) return;
    int r = idx / EE;
    atomicAdd(&cnt[r * NN + dst[idx]], 1);
}

__global__ __launch_bounds__(SCAN_CHUNK) void k_scan1(const int* __restrict__ cnt,
                                                      int* __restrict__ row_ptr,
                                                      int* __restrict__ blk) {
    __shared__ int sh[SCAN_CHUNK];
    const int tid = threadIdx.x;
    const int i = blockIdx.x * SCAN_CHUNK + tid;
    int v = (i < RN) ? cnt[i] : 0;
    sh[tid] = v;
    __syncthreads();
    for (int off = 1; off < SCAN_CHUNK; off <<= 1) {
        int t = (tid >= off) ? sh[tid - off] : 0;
        __syncthreads();
        sh[tid] += t;
        __syncthreads();
    }
    if (i < RN) row_ptr[i] = sh[tid] - v;
    if (tid == SCAN_CHUNK - 1) blk[blockIdx.x] = sh[tid];
}

__global__ __launch_bounds__(256) void k_scan2(int* __restrict__ blk) {
    __shared__ int sh[256];
    const int tid = threadIdx.x;
    int v = (tid < NBLK) ? blk[tid] : 0;
    sh[tid] = v;
    __syncthreads();
    for (int off = 1; off < 256; off <<= 1) {
        int t = (tid >= off) ? sh[tid - off] : 0;
        __syncthreads();
        sh[tid] += t;
        __syncthreads();
    }
    if (tid < NBLK) blk[tid] = sh[tid] - v;
}

__global__ void k_scan3(int* __restrict__ row_ptr, int* __restrict__ cursor,
                        const int* __restrict__ blk) {
    int i = blockIdx.x * blockDim.x + threadIdx.x;
    if (i < RN) {
        int v = row_ptr[i] + blk[i / SCAN_CHUNK];
        row_ptr[i] = v;
        cursor[i] = v;
    }
    if (i == 0) row_ptr[RN] = RR * EE;
}

__global__ void k_fill(const int* __restrict__ dst, int* __restrict__ cursor,
                       int* __restrict__ eid) {
    int idx = blockIdx.x * blockDim.x + threadIdx.x;
    if (idx >= RR * EE) return;
    int r = idx / EE;
    int e = idx - r * EE;
    int pos = atomicAdd(&cursor[r * NN + dst[idx]], 1);
    eid[pos] = e;
}

__global__ void k_sortseg(const int* __restrict__ row_ptr, int* __restrict__ eid) {
    int s = blockIdx.x * blockDim.x + threadIdx.x;
    if (s >= RN) return;
    int p0 = row_ptr[s], p1 = row_ptr[s + 1];
    for (int i = p0; i < p1 - 1; ++i) {
        int mn = eid[i], mi = i;
        for (int k = i + 1; k < p1; ++k) {
            int v = eid[k];
            if (v < mn) { mn = v; mi = k; }
        }
        eid[mi] = eid[i];
        eid[i] = mn;
    }
}

// ---- fused gather: online segment softmax + message agg + gate + crossing ----
__global__ __launch_bounds__(256) void k_gather_cross(
    const int* __restrict__ src, const int* __restrict__ row_ptr,
    const int* __restrict__ eid,
    const float* __restrict__ sc_src, const float* __restrict__ sc_dst,
    const ushort_t* __restrict__ s, const ushort_t* __restrict__ res_buf,
    const float* __restrict__ res_alpha, const float* __restrict__ crossW,
    float* __restrict__ out) {
    int n = blockIdx.x * 4 + (threadIdx.x >> 6);
    if (n >= NN) return;
    const int lane = threadIdx.x & 63;
    const int g = lane >> 5;
    const int j = lane & 31;
    const int h = j >> 2;

    const int seg = g * NN + n;
    const int p0 = row_ptr[seg], p1 = row_ptr[seg + 1];
    const float sd = sc_dst[(size_t)seg * HH + h];

    float mx = -INFINITY, den = 0.f;
    float4 acc = {0.f, 0.f, 0.f, 0.f};
    for (int p = p0; p < p1; ++p) {
        int sr = src[g * EE + eid[p]];
        float v = lrelu(sc_src[(size_t)(g * NN + sr) * HH + h] + sd);
        float e;
        if (v > mx) {
            float sc = __expf(mx - v);   // first iter: exp(-inf) = 0
            den *= sc;
            acc.x *= sc; acc.y *= sc; acc.z *= sc; acc.w *= sc;
            mx = v;
            e = 1.f;
        } else {
            e = __expf(v - mx);
        }
        den += e;
        ushort4 s4 = *(const ushort4*)(s + (size_t)(g * NN + sr) * DD + j * 4);
        acc.x = fmaf(e, bf2f(s4.x), acc.x);
        acc.y = fmaf(e, bf2f(s4.y), acc.y);
        acc.z = fmaf(e, bf2f(s4.z), acc.z);
        acc.w = fmaf(e, bf2f(s4.w), acc.w);
    }
    float inv = (p1 > p0) ? 1.f / den : 0.f;

    float gate = 1.f / (1.f + __expf(-res_alpha[0]));
    ushort4 r4u = *(const ushort4*)(res_buf + (size_t)n * DD + j * 4);
    float4 og;
    og.x = fmaf(acc.x * inv, gate, bf2f(r4u.x) * (1.f - gate));
    og.y = fmaf(acc.y * inv, gate, bf2f(r4u.y) * (1.f - gate));
    og.z = fmaf(acc.z * inv, gate, bf2f(r4u.z) * (1.f - gate));
    og.w = fmaf(acc.w * inv, gate, bf2f(r4u.w) * (1.f - gate));

    float4 oo;
    oo.x = __shfl_xor(og.x, 32);
    oo.y = __shfl_xor(og.y, 32);
    oo.z = __shfl_xor(og.z, 32);
    oo.w = __shfl_xor(og.w, 32);

    float4 cw = *(const float4*)(crossW + g * DD + j * 4);
    float ds_ = og.x * cw.x + og.y * cw.y + og.z * cw.z + og.w * cw.w;
    float do_ = oo.x * cw.x + oo.y * cw.y + oo.z * cw.z + oo.w * cw.w;
    ds_ += __shfl_xor(ds_, 1); ds_ += __shfl_xor(ds_, 2);
    do_ += __shfl_xor(do_, 1); do_ += __shfl_xor(do_, 2);
    float l0 = lrelu(ds_), l1 = lrelu(do_);
    float mm = fmaxf(l0, l1);
    float e0 = __expf(l0 - mm), e1 = __expf(l1 - mm);
    float winv = 1.f / (e0 + e1);
    float w0 = e0 * winv, w1 = e1 * winv;

    float4 o;
    o.x = w0 * og.x + w1 * oo.x;
    o.y = w0 * og.y + w1 * oo.y;
    o.z = w0 * og.z + w1 * oo.z;
    o.w = w0 * og.w + w1 * oo.w;
    *(float4*)(out + (size_t)(g * NN + n) * DD + j * 4) = o;
}

extern "C" void kernel_launch(void* const* d_in, const int* in_sizes, int n_in,
                              void* d_out, int out_size, void* d_ws, size_t ws_size,
                              hipStream_t stream) {
    const float* x        = (const float*)d_in[0];
    const int*   src      = (const int*)d_in[1];
    const int*   dst      = (const int*)d_in[2];
    const float* rel_emb  = (const float*)d_in[3];
    const float* Wp       = (const float*)d_in[4];
    const float* bp       = (const float*)d_in[5];
    const float* Wn       = (const float*)d_in[6];
    const float* bn       = (const float*)d_in[7];
    const float* Wsrc     = (const float*)d_in[8];
    const float* bsrc     = (const float*)d_in[9];
    const float* Wrel     = (const float*)d_in[10];
    const float* resW     = (const float*)d_in[11];
    const float* resb     = (const float*)d_in[12];
    const float* res_alpha= (const float*)d_in[13];
    const float* crossW   = (const float*)d_in[14];
    const float* Wprop    = (const float*)d_in[15];
    const float* bprop    = (const float*)d_in[16];

    float* out = (float*)d_out;

    // workspace layout: bf16 buffers first, then f32, then packed weights, ints
    ushort_t* s_bf   = (ushort_t*)d_ws;                    // R*N*D ushorts
    ushort_t* res_bf = s_bf + (size_t)RR * NN * DD;        // N*D ushorts
    float* fbase   = (float*)(res_bf + (size_t)NN * DD);
    float* sc_src  = fbase;                                // R*N*H
    float* sc_dst  = sc_src  + (size_t)RR * NN * HH;       // R*N*H
    float* avec    = sc_dst  + (size_t)RR * NN * HH;       // 512
    float* Wpn     = avec    + 512;                        // 16384
    float* Wres_c  = Wpn     + DD * DD;                    // 16384
    float* Ws_c    = Wres_c  + DD * DD;                    // 2*16384
    float* VdstT   = Ws_c    + (size_t)RR * DD * DD;       // 16*128
    float* bpn     = VdstT   + 16 * DD;                    // 128
    float* bres_c  = bpn     + DD;                         // 128
    float* bs_c    = bres_c  + DD;                         // 256
    float* cdst    = bs_c    + RR * DD;                    // 16
    short* Wpk     = (short*)(cdst + 16);                  // 25*4*64*8 = 51200
    int*   cnt     = (int*)(Wpk + (size_t)NT * 4 * 64 * 8);// RN
    int*   row_ptr = cnt + RN;                             // RN + 1
    int*   cursor  = row_ptr + RN + 1;                     // RN
    int*   eid     = cursor + RN;                          // R*E
    int*   blk     = eid + RR * EE;                        // NBLK

    k_prep<<<1, 256, 0, stream>>>(rel_emb, Wrel, Wprop, bprop, avec,
                                  out + (size_t)RR * NN * DD);
    k_compose1<<<DD, DD, 0, stream>>>(Wp, bp, Wn, bn, resW, resb,
                                      Wpn, bpn, Wres_c, bres_c);
    k_compose2<<<dim3(RR, DD), DD, 0, stream>>>(Wpn, bpn, Wsrc, bsrc, avec,
                                                Ws_c, bs_c, VdstT, cdst);
    k_pack<<<NT, 256, 0, stream>>>(Ws_c, Wres_c, VdstT, Wpk);
    k_node3<<<NN / 32, 128, 0, stream>>>(x, Wpk, bs_c, bres_c, avec, cdst,
                                         s_bf, res_bf, sc_src, sc_dst);
    k_zero<<<(RN + 255) / 256, 256, 0, stream>>>(cnt);
    k_count<<<(RR * EE + 255) / 256, 256, 0, stream>>>(dst, cnt);
    k_scan1<<<NBLK, SCAN_CHUNK, 0, stream>>>(cnt, row_ptr, blk);
    k_scan2<<<1, 256, 0, stream>>>(blk);
    k_scan3<<<(RN + 255) / 256, 256, 0, stream>>>(row_ptr, cursor, blk);
    k_fill<<<(RR * EE + 255) / 256, 256, 0, stream>>>(dst, cursor, eid);
    k_sortseg<<<(RN + 255) / 256, 256, 0, stream>>>(row_ptr, eid);
    k_gather_cross<<<(NN + 3) / 4, 256, 0, stream>>>(src, row_ptr, eid, sc_src, sc_dst,
                                                     s_bf, res_bf, res_alpha, crossW,
                                                     out);
}

// Round 7
// 378.243 us; speedup vs baseline: 8.8646x; 1.1434x over previous
//
#include <hip/hip_runtime.h>
#include <math.h>

#define NN 100000
#define EE 600000
#define RR 2
#define DD 128
#define HH 8
#define DHH 16
#define RN (RR * NN)
#define SCAN_CHUNK 1024
#define NBLK ((RN + SCAN_CHUNK - 1) / SCAN_CHUNK)   // 196
#define NT 25   // N-tiles in node GEMM: 8 (s0) + 8 (s1) + 8 (res) + 1 (sc_dst)

typedef unsigned short ushort_t;
typedef short bf16x8 __attribute__((ext_vector_type(8)));
typedef float f32x4 __attribute__((ext_vector_type(4)));

__device__ __forceinline__ float lrelu(float v) { return v >= 0.f ? v : 0.2f * v; }

__device__ __forceinline__ float reduce16(float p) {
    p += __shfl_xor(p, 1);
    p += __shfl_xor(p, 2);
    p += __shfl_xor(p, 4);
    p += __shfl_xor(p, 8);
    return p;
}

// f32 -> bf16 (round to nearest even), bf16 -> f32 (exact)
__device__ __forceinline__ ushort_t f2bf(float f) {
    unsigned int u = __float_as_uint(f);
    u = (u + 0x7FFFu + ((u >> 16) & 1u)) >> 16;
    return (ushort_t)u;
}
__device__ __forceinline__ float bf2f(ushort_t u) {
    return __uint_as_float(((unsigned int)u) << 16);
}

// ---- prep: a = rel_emb @ Wrel  [R*256], rel_out = rel_emb @ Wprop + bprop ----
__global__ void k_prep(const float* __restrict__ rel_emb, const float* __restrict__ Wrel,
                       const float* __restrict__ Wprop, const float* __restrict__ bprop,
                       float* __restrict__ avec, float* __restrict__ rel_out) {
    int tid = threadIdx.x;
    for (int idx = tid; idx < RR * 256; idx += 256) {
        int r = idx >> 8, o = idx & 255;
        float acc = 0.f;
        for (int i = 0; i < 64; ++i)
            acc += rel_emb[r * 64 + i] * Wrel[(r * 64 + i) * 256 + o];
        avec[idx] = acc;
    }
    {   // rel_out: 256 outputs, one per thread
        int r = tid >> 7, o = tid & 127;
        float acc = bprop[tid];
        for (int i = 0; i < 64; ++i)
            acc += rel_emb[r * 64 + i] * Wprop[(r * 64 + i) * 128 + o];
        rel_out[tid] = acc;
    }
}

// ---- compose stage 1: Wpn = Wp@Wn, Wres_c = Wp@resW (+ bias folds) ----
__global__ __launch_bounds__(128) void k_compose1(
    const float* __restrict__ Wp, const float* __restrict__ bp,
    const float* __restrict__ Wn, const float* __restrict__ bn,
    const float* __restrict__ resW, const float* __restrict__ resb,
    float* __restrict__ Wpn, float* __restrict__ bpn,
    float* __restrict__ Wres_c, float* __restrict__ bres_c) {
    __shared__ float row[DD];
    const int rrow = blockIdx.x, tid = threadIdx.x;
    row[tid] = Wp[rrow * DD + tid];
    __syncthreads();
    float acc1 = 0.f, acc2 = 0.f;
    for (int k = 0; k < DD; ++k) {
        float wv = row[k];
        acc1 = fmaf(wv, Wn[k * DD + tid], acc1);
        acc2 = fmaf(wv, resW[k * DD + tid], acc2);
    }
    Wpn[rrow * DD + tid] = acc1;
    Wres_c[rrow * DD + tid] = acc2;
    if (rrow == 0) {
        float b1 = 0.f, b2 = 0.f;
        for (int k = 0; k < DD; ++k) {
            b1 = fmaf(bp[k], Wn[k * DD + tid], b1);
            b2 = fmaf(bp[k], resW[k * DD + tid], b2);
        }
        bpn[tid] = b1 + bn[tid];
        bres_c[tid] = b2 + resb[tid];
    }
}

// ---- compose stage 2: Ws_c[r] = Wpn@Wsrc_r (+bias), VdstT = Wpn-projected a1 ----
__global__ __launch_bounds__(128) void k_compose2(
    const float* __restrict__ Wpn, const float* __restrict__ bpn,
    const float* __restrict__ Wsrc, const float* __restrict__ bsrc,
    const float* __restrict__ avec,
    float* __restrict__ Ws_c, float* __restrict__ bs_c,
    float* __restrict__ VdstT, float* __restrict__ cdst) {
    __shared__ float row[DD];
    const int rel = blockIdx.x, rrow = blockIdx.y, tid = threadIdx.x;
    row[tid] = Wpn[rrow * DD + tid];
    __syncthreads();
    const float* W = Wsrc + (size_t)rel * DD * DD;
    float acc = 0.f;
    for (int k = 0; k < DD; ++k) acc = fmaf(row[k], W[k * DD + tid], acc);
    Ws_c[(size_t)rel * DD * DD + rrow * DD + tid] = acc;
    if (tid < HH) {  // head = tid
        float v = 0.f;
        for (int d = 0; d < 16; ++d)
            v += row[tid * 16 + d] * avec[rel * 256 + tid * 32 + 16 + d];
        VdstT[(rel * HH + tid) * DD + rrow] = v;
    }
    if (rrow == 0) {
        float b = 0.f;
        for (int k = 0; k < DD; ++k) b = fmaf(bpn[k], W[k * DD + tid], b);
        bs_c[rel * DD + tid] = b + bsrc[rel * DD + tid];
        if (rel == 0 && tid < 16) {
            int r2 = tid >> 3, h2 = tid & 7;
            float c2 = 0.f;
            for (int d = 0; d < 16; ++d)
                c2 += bpn[h2 * 16 + d] * avec[r2 * 256 + h2 * 32 + 16 + d];
            cdst[tid] = c2;
        }
    }
}

// ---- pack composed weights into MFMA B-fragment layout (bf16) ----
__global__ __launch_bounds__(256) void k_pack(
    const float* __restrict__ Ws_c, const float* __restrict__ Wres_c,
    const float* __restrict__ VdstT, short* __restrict__ Wpk) {
    const int t = blockIdx.x;
    const int kt = threadIdx.x >> 6;
    const int l = threadIdx.x & 63;
    const int c16 = l & 15;
    bf16x8 v;
    #pragma unroll
    for (int j = 0; j < 8; ++j) {
        int k = kt * 32 + (l >> 4) * 8 + j;
        float f;
        if (t < 24) {
            int m = t >> 3;                    // 0=Ws0, 1=Ws1, 2=Wres
            int col = (t & 7) * 16 + c16;
            const float* W = (m == 0) ? Ws_c : (m == 1) ? Ws_c + DD * DD : Wres_c;
            f = W[k * DD + col];
        } else {
            f = VdstT[c16 * DD + k];
        }
        v[j] = (short)f2bf(f);
    }
    *(bf16x8*)(Wpk + ((size_t)(t * 4 + kt) * 64 + l) * 8) = v;
}

// ---- node GEMM via MFMA: [32 nodes/block] x @ [Ws0|Ws1|Wres|Vdst] ----
__global__ __launch_bounds__(128) void k_node3(
    const float* __restrict__ x, const short* __restrict__ Wpk,
    const float* __restrict__ bs_c, const float* __restrict__ bres_c,
    const float* __restrict__ avec, const float* __restrict__ cdst,
    ushort_t* __restrict__ s_out, ushort_t* __restrict__ res_out,
    float* __restrict__ sc_src, float* __restrict__ sc_dst) {
    const int tid = threadIdx.x;
    const int l = tid & 63;
    const int w = tid >> 6;
    const int m16 = l & 15, g4 = l >> 4;
    const int nw0 = blockIdx.x * 32 + w * 16;

    bf16x8 af[4];
    const float* xrow = x + (size_t)(nw0 + m16) * DD + g4 * 8;
    #pragma unroll
    for (int kt = 0; kt < 4; ++kt) {
        float4 v0 = *(const float4*)(xrow + kt * 32);
        float4 v1 = *(const float4*)(xrow + kt * 32 + 4);
        af[kt][0] = (short)f2bf(v0.x); af[kt][1] = (short)f2bf(v0.y);
        af[kt][2] = (short)f2bf(v0.z); af[kt][3] = (short)f2bf(v0.w);
        af[kt][4] = (short)f2bf(v1.x); af[kt][5] = (short)f2bf(v1.y);
        af[kt][6] = (short)f2bf(v1.z); af[kt][7] = (short)f2bf(v1.w);
    }

    for (int t = 0; t < NT; ++t) {
        f32x4 acc = {0.f, 0.f, 0.f, 0.f};
        #pragma unroll
        for (int kt = 0; kt < 4; ++kt) {
            bf16x8 b = *(const bf16x8*)(Wpk + ((size_t)(t * 4 + kt) * 64 + l) * 8);
            acc = __builtin_amdgcn_mfma_f32_16x16x32_bf16(af[kt], b, acc, 0, 0, 0);
        }
        if (t < 16) {
            const int rel = t >> 3, head = t & 7;
            const float a0v = avec[rel * 256 + head * 32 + m16];
            const float bb = bs_c[rel * DD + head * 16 + m16];
            #pragma unroll
            for (int r = 0; r < 4; ++r) {
                const int node = nw0 + g4 * 4 + r;
                float sv = acc[r] + bb;
                s_out[((size_t)rel * NN + node) * DD + head * 16 + m16] = f2bf(sv);
                float p = reduce16(sv * a0v);
                if (m16 == 0) sc_src[((size_t)rel * NN + node) * HH + head] = p;
            }
        } else if (t < 24) {
            const int col = (t - 16) * 16 + m16;
            const float bb = bres_c[col];
            #pragma unroll
            for (int r = 0; r < 4; ++r) {
                const int node = nw0 + g4 * 4 + r;
                res_out[(size_t)node * DD + col] = f2bf(acc[r] + bb);
            }
        } else {
            const int rel = m16 >> 3, head = m16 & 7;
            const float bb = cdst[m16];
            #pragma unroll
            for (int r = 0; r < 4; ++r) {
                const int node = nw0 + g4 * 4 + r;
                sc_dst[((size_t)rel * NN + node) * HH + head] = acc[r] + bb;
            }
        }
    }
}

// ---- CSR build ----
__global__ void k_zero(int* __restrict__ cnt) {
    int i = blockIdx.x * blockDim.x + threadIdx.x;
    if (i < RN) cnt[i] = 0;
}

__global__ void k_count(const int* __restrict__ dst, int* __restrict__ cnt) {
    int idx = blockIdx.x * blockDim.x + threadIdx.x;
    if (idx >= RR * EE) return;
    int r = idx / EE;
    atomicAdd(&cnt[r * NN + dst[idx]], 1);
}

__global__ __launch_bounds__(SCAN_CHUNK) void k_scan1(const int* __restrict__ cnt,
                                                      int* __restrict__ row_ptr,
                                                      int* __restrict__ blk) {
    __shared__ int sh[SCAN_CHUNK];
    const int tid = threadIdx.x;
    const int i = blockIdx.x * SCAN_CHUNK + tid;
    int v = (i < RN) ? cnt[i] : 0;
    sh[tid] = v;
    __syncthreads();
    for (int off = 1; off < SCAN_CHUNK; off <<= 1) {
        int t = (tid >= off) ? sh[tid - off] : 0;
        __syncthreads();
        sh[tid] += t;
        __syncthreads();
    }
    if (i < RN) row_ptr[i] = sh[tid] - v;
    if (tid == SCAN_CHUNK - 1) blk[blockIdx.x] = sh[tid];
}

__global__ __launch_bounds__(256) void k_scan2(int* __restrict__ blk) {
    __shared__ int sh[256];
    const int tid = threadIdx.x;
    int v = (tid < NBLK) ? blk[tid] : 0;
    sh[tid] = v;
    __syncthreads();
    for (int off = 1; off < 256; off <<= 1) {
        int t = (tid >= off) ? sh[tid - off] : 0;
        __syncthreads();
        sh[tid] += t;
        __syncthreads();
    }
    if (tid < NBLK) blk[tid] = sh[tid] - v;
}

__global__ void k_scan3(int* __restrict__ row_ptr, int* __restrict__ cursor,
                        const int* __restrict__ blk) {
    int i = blockIdx.x * blockDim.x + threadIdx.x;
    if (i < RN) {
        int v = row_ptr[i] + blk[i / SCAN_CHUNK];
        row_ptr[i] = v;
        cursor[i] = v;
    }
    if (i == 0) row_ptr[RN] = RR * EE;
}

// fill stores the SRC VALUE per CSR slot (no eid indirection in the gather)
__global__ void k_fill(const int* __restrict__ src, const int* __restrict__ dst,
                       int* __restrict__ cursor, int* __restrict__ esrc) {
    int idx = blockIdx.x * blockDim.x + threadIdx.x;
    if (idx >= RR * EE) return;
    int r = idx / EE;
    int pos = atomicAdd(&cursor[r * NN + dst[idx]], 1);
    esrc[pos] = src[idx];
}

// deterministic order within each segment: sort by src value (duplicates
// are interchangeable -> bit-identical result regardless of arrival order)
__global__ void k_sortseg(const int* __restrict__ row_ptr, int* __restrict__ esrc) {
    int s = blockIdx.x * blockDim.x + threadIdx.x;
    if (s >= RN) return;
    int p0 = row_ptr[s], p1 = row_ptr[s + 1];
    for (int i = p0; i < p1 - 1; ++i) {
        int mn = esrc[i], mi = i;
        for (int k = i + 1; k < p1; ++k) {
            int v = esrc[k];
            if (v < mn) { mn = v; mi = k; }
        }
        esrc[mi] = esrc[i];
        esrc[i] = mn;
    }
}

// ---- fused gather: two-pass segment softmax + message agg + gate + crossing ----
// One wave64 per node: lanes 0-31 -> relation 0, lanes 32-63 -> relation 1.
// Lane j (0..31) within group handles columns 4j..4j+3 (head h = j>>2).
__global__ __launch_bounds__(256) void k_gather_cross(
    const int* __restrict__ esrc, const int* __restrict__ row_ptr,
    const float* __restrict__ sc_src, const float* __restrict__ sc_dst,
    const ushort_t* __restrict__ s, const ushort_t* __restrict__ res_buf,
    const float* __restrict__ res_alpha, const float* __restrict__ crossW,
    float* __restrict__ out) {
    int n = blockIdx.x * 4 + (threadIdx.x >> 6);
    if (n >= NN) return;
    const int lane = threadIdx.x & 63;
    const int g = lane >> 5;
    const int j = lane & 31;
    const int h = j >> 2;

    const int seg = g * NN + n;
    const int p0 = row_ptr[seg], p1 = row_ptr[seg + 1];
    const float sd = sc_dst[(size_t)seg * HH + h];

    // pass 1: segment max over scores (warms sc lines)
    float mx = -INFINITY;
    for (int p = p0; p < p1; ++p) {
        int sr = esrc[p];
        float v = lrelu(sc_src[(size_t)(g * NN + sr) * HH + h] + sd);
        mx = fmaxf(mx, v);
    }

    // pass 2: branch-free exp + weighted accumulate, unrolled x2
    float den = 0.f;
    float4 acc = {0.f, 0.f, 0.f, 0.f};
    int p = p0;
    for (; p + 1 < p1; p += 2) {
        int sr0 = esrc[p], sr1 = esrc[p + 1];
        ushort4 s40 = *(const ushort4*)(s + (size_t)(g * NN + sr0) * DD + j * 4);
        ushort4 s41 = *(const ushort4*)(s + (size_t)(g * NN + sr1) * DD + j * 4);
        float v0 = lrelu(sc_src[(size_t)(g * NN + sr0) * HH + h] + sd);
        float v1 = lrelu(sc_src[(size_t)(g * NN + sr1) * HH + h] + sd);
        float e0 = __expf(v0 - mx);
        float e1 = __expf(v1 - mx);
        den += e0; den += e1;
        acc.x = fmaf(e0, bf2f(s40.x), acc.x); acc.x = fmaf(e1, bf2f(s41.x), acc.x);
        acc.y = fmaf(e0, bf2f(s40.y), acc.y); acc.y = fmaf(e1, bf2f(s41.y), acc.y);
        acc.z = fmaf(e0, bf2f(s40.z), acc.z); acc.z = fmaf(e1, bf2f(s41.z), acc.z);
        acc.w = fmaf(e0, bf2f(s40.w), acc.w); acc.w = fmaf(e1, bf2f(s41.w), acc.w);
    }
    if (p < p1) {
        int sr0 = esrc[p];
        ushort4 s40 = *(const ushort4*)(s + (size_t)(g * NN + sr0) * DD + j * 4);
        float v0 = lrelu(sc_src[(size_t)(g * NN + sr0) * HH + h] + sd);
        float e0 = __expf(v0 - mx);
        den += e0;
        acc.x = fmaf(e0, bf2f(s40.x), acc.x);
        acc.y = fmaf(e0, bf2f(s40.y), acc.y);
        acc.z = fmaf(e0, bf2f(s40.z), acc.z);
        acc.w = fmaf(e0, bf2f(s40.w), acc.w);
    }
    float inv = (p1 > p0) ? 1.f / den : 0.f;

    float gate = 1.f / (1.f + __expf(-res_alpha[0]));
    ushort4 r4u = *(const ushort4*)(res_buf + (size_t)n * DD + j * 4);
    float4 og;
    og.x = fmaf(acc.x * inv, gate, bf2f(r4u.x) * (1.f - gate));
    og.y = fmaf(acc.y * inv, gate, bf2f(r4u.y) * (1.f - gate));
    og.z = fmaf(acc.z * inv, gate, bf2f(r4u.z) * (1.f - gate));
    og.w = fmaf(acc.w * inv, gate, bf2f(r4u.w) * (1.f - gate));

    float4 oo;
    oo.x = __shfl_xor(og.x, 32);
    oo.y = __shfl_xor(og.y, 32);
    oo.z = __shfl_xor(og.z, 32);
    oo.w = __shfl_xor(og.w, 32);

    float4 cw = *(const float4*)(crossW + g * DD + j * 4);
    float ds_ = og.x * cw.x + og.y * cw.y + og.z * cw.z + og.w * cw.w;
    float do_ = oo.x * cw.x + oo.y * cw.y + oo.z * cw.z + oo.w * cw.w;
    ds_ += __shfl_xor(ds_, 1); ds_ += __shfl_xor(ds_, 2);
    do_ += __shfl_xor(do_, 1); do_ += __shfl_xor(do_, 2);
    float l0 = lrelu(ds_), l1 = lrelu(do_);
    float mm = fmaxf(l0, l1);
    float e0 = __expf(l0 - mm), e1 = __expf(l1 - mm);
    float winv = 1.f / (e0 + e1);
    float w0 = e0 * winv, w1 = e1 * winv;

    float4 o;
    o.x = w0 * og.x + w1 * oo.x;
    o.y = w0 * og.y + w1 * oo.y;
    o.z = w0 * og.z + w1 * oo.z;
    o.w = w0 * og.w + w1 * oo.w;
    *(float4*)(out + (size_t)(g * NN + n) * DD + j * 4) = o;
}

extern "C" void kernel_launch(void* const* d_in, const int* in_sizes, int n_in,
                              void* d_out, int out_size, void* d_ws, size_t ws_size,
                              hipStream_t stream) {
    const float* x        = (const float*)d_in[0];
    const int*   src      = (const int*)d_in[1];
    const int*   dst      = (const int*)d_in[2];
    const float* rel_emb  = (const float*)d_in[3];
    const float* Wp       = (const float*)d_in[4];
    const float* bp       = (const float*)d_in[5];
    const float* Wn       = (const float*)d_in[6];
    const float* bn       = (const float*)d_in[7];
    const float* Wsrc     = (const float*)d_in[8];
    const float* bsrc     = (const float*)d_in[9];
    const float* Wrel     = (const float*)d_in[10];
    const float* resW     = (const float*)d_in[11];
    const float* resb     = (const float*)d_in[12];
    const float* res_alpha= (const float*)d_in[13];
    const float* crossW   = (const float*)d_in[14];
    const float* Wprop    = (const float*)d_in[15];
    const float* bprop    = (const float*)d_in[16];

    float* out = (float*)d_out;

    // workspace layout: bf16 buffers first, then f32, then packed weights, ints
    ushort_t* s_bf   = (ushort_t*)d_ws;                    // R*N*D ushorts
    ushort_t* res_bf = s_bf + (size_t)RR * NN * DD;        // N*D ushorts
    float* fbase   = (float*)(res_bf + (size_t)NN * DD);
    float* sc_src  = fbase;                                // R*N*H
    float* sc_dst  = sc_src  + (size_t)RR * NN * HH;       // R*N*H
    float* avec    = sc_dst  + (size_t)RR * NN * HH;       // 512
    float* Wpn     = avec    + 512;                        // 16384
    float* Wres_c  = Wpn     + DD * DD;                    // 16384
    float* Ws_c    = Wres_c  + DD * DD;                    // 2*16384
    float* VdstT   = Ws_c    + (size_t)RR * DD * DD;       // 16*128
    float* bpn     = VdstT   + 16 * DD;                    // 128
    float* bres_c  = bpn     + DD;                         // 128
    float* bs_c    = bres_c  + DD;                         // 256
    float* cdst    = bs_c    + RR * DD;                    // 16
    short* Wpk     = (short*)(cdst + 16);                  // 25*4*64*8 = 51200
    int*   cnt     = (int*)(Wpk + (size_t)NT * 4 * 64 * 8);// RN
    int*   row_ptr = cnt + RN;                             // RN + 1
    int*   cursor  = row_ptr + RN + 1;                     // RN
    int*   esrc    = cursor + RN;                          // R*E
    int*   blk     = esrc + RR * EE;                       // NBLK

    k_prep<<<1, 256, 0, stream>>>(rel_emb, Wrel, Wprop, bprop, avec,
                                  out + (size_t)RR * NN * DD);
    k_compose1<<<DD, DD, 0, stream>>>(Wp, bp, Wn, bn, resW, resb,
                                      Wpn, bpn, Wres_c, bres_c);
    k_compose2<<<dim3(RR, DD), DD, 0, stream>>>(Wpn, bpn, Wsrc, bsrc, avec,
                                                Ws_c, bs_c, VdstT, cdst);
    k_pack<<<NT, 256, 0, stream>>>(Ws_c, Wres_c, VdstT, Wpk);
    k_node3<<<NN / 32, 128, 0, stream>>>(x, Wpk, bs_c, bres_c, avec, cdst,
                                         s_bf, res_bf, sc_src, sc_dst);
    k_zero<<<(RN + 255) / 256, 256, 0, stream>>>(cnt);
    k_count<<<(RR * EE + 255) / 256, 256, 0, stream>>>(dst, cnt);
    k_scan1<<<NBLK, SCAN_CHUNK, 0, stream>>>(cnt, row_ptr, blk);
    k_scan2<<<1, 256, 0, stream>>>(blk);
    k_scan3<<<(RN + 255) / 256, 256, 0, stream>>>(row_ptr, cursor, blk);
    k_fill<<<(RR * EE + 255) / 256, 256, 0, stream>>>(src, dst, cursor, esrc);
    k_sortseg<<<(RN + 255) / 256, 256, 0, stream>>>(row_ptr, esrc);
    k_gather_cross<<<(NN + 3) / 4, 256, 0, stream>>>(esrc, row_ptr, sc_src, sc_dst,
                                                     s_bf, res_bf, res_alpha, crossW,
                                                     out);
}

// Round 8
// 372.851 us; speedup vs baseline: 8.9928x; 1.0145x over previous
//
#include <hip/hip_runtime.h>
#include <math.h>

#define NN 100000
#define EE 600000
#define RR 2
#define DD 128
#define HH 8
#define DHH 16
#define RN (RR * NN)
#define SCAN_CHUNK 1024
#define NBLK ((RN + SCAN_CHUNK - 1) / SCAN_CHUNK)   // 196
#define NT 25     // N-tiles in node GEMM: 8 (s0) + 8 (s1) + 8 (res) + 1 (sc_dst)
#define MTOT 6250 // total m-tiles (16 nodes each)
#define MT 4      // m-tiles per wave
#define SEGCAP 16

typedef unsigned short ushort_t;
typedef short bf16x8 __attribute__((ext_vector_type(8)));
typedef float f32x4 __attribute__((ext_vector_type(4)));

__device__ __forceinline__ float lrelu(float v) { return v >= 0.f ? v : 0.2f * v; }

__device__ __forceinline__ float reduce16(float p) {
    p += __shfl_xor(p, 1);
    p += __shfl_xor(p, 2);
    p += __shfl_xor(p, 4);
    p += __shfl_xor(p, 8);
    return p;
}

// f32 -> bf16 (round to nearest even), bf16 -> f32 (exact)
__device__ __forceinline__ ushort_t f2bf(float f) {
    unsigned int u = __float_as_uint(f);
    u = (u + 0x7FFFu + ((u >> 16) & 1u)) >> 16;
    return (ushort_t)u;
}
__device__ __forceinline__ float bf2f(ushort_t u) {
    return __uint_as_float(((unsigned int)u) << 16);
}

// ---- prep: a = rel_emb @ Wrel  [R*256], rel_out = rel_emb @ Wprop + bprop ----
__global__ void k_prep(const float* __restrict__ rel_emb, const float* __restrict__ Wrel,
                       const float* __restrict__ Wprop, const float* __restrict__ bprop,
                       float* __restrict__ avec, float* __restrict__ rel_out) {
    int tid = threadIdx.x;
    for (int idx = tid; idx < RR * 256; idx += 256) {
        int r = idx >> 8, o = idx & 255;
        float acc = 0.f;
        for (int i = 0; i < 64; ++i)
            acc += rel_emb[r * 64 + i] * Wrel[(r * 64 + i) * 256 + o];
        avec[idx] = acc;
    }
    {   // rel_out: 256 outputs, one per thread
        int r = tid >> 7, o = tid & 127;
        float acc = bprop[tid];
        for (int i = 0; i < 64; ++i)
            acc += rel_emb[r * 64 + i] * Wprop[(r * 64 + i) * 128 + o];
        rel_out[tid] = acc;
    }
}

// ---- compose stage 1: Wpn = Wp@Wn, Wres_c = Wp@resW (+ bias folds) ----
__global__ __launch_bounds__(128) void k_compose1(
    const float* __restrict__ Wp, const float* __restrict__ bp,
    const float* __restrict__ Wn, const float* __restrict__ bn,
    const float* __restrict__ resW, const float* __restrict__ resb,
    float* __restrict__ Wpn, float* __restrict__ bpn,
    float* __restrict__ Wres_c, float* __restrict__ bres_c) {
    __shared__ float row[DD];
    const int rrow = blockIdx.x, tid = threadIdx.x;
    row[tid] = Wp[rrow * DD + tid];
    __syncthreads();
    float acc1 = 0.f, acc2 = 0.f;
    for (int k = 0; k < DD; ++k) {
        float wv = row[k];
        acc1 = fmaf(wv, Wn[k * DD + tid], acc1);
        acc2 = fmaf(wv, resW[k * DD + tid], acc2);
    }
    Wpn[rrow * DD + tid] = acc1;
    Wres_c[rrow * DD + tid] = acc2;
    if (rrow == 0) {
        float b1 = 0.f, b2 = 0.f;
        for (int k = 0; k < DD; ++k) {
            b1 = fmaf(bp[k], Wn[k * DD + tid], b1);
            b2 = fmaf(bp[k], resW[k * DD + tid], b2);
        }
        bpn[tid] = b1 + bn[tid];
        bres_c[tid] = b2 + resb[tid];
    }
}

// ---- compose stage 2: Ws_c[r] = Wpn@Wsrc_r (+bias), VdstT = Wpn-projected a1 ----
__global__ __launch_bounds__(128) void k_compose2(
    const float* __restrict__ Wpn, const float* __restrict__ bpn,
    const float* __restrict__ Wsrc, const float* __restrict__ bsrc,
    const float* __restrict__ avec,
    float* __restrict__ Ws_c, float* __restrict__ bs_c,
    float* __restrict__ VdstT, float* __restrict__ cdst) {
    __shared__ float row[DD];
    const int rel = blockIdx.x, rrow = blockIdx.y, tid = threadIdx.x;
    row[tid] = Wpn[rrow * DD + tid];
    __syncthreads();
    const float* W = Wsrc + (size_t)rel * DD * DD;
    float acc = 0.f;
    for (int k = 0; k < DD; ++k) acc = fmaf(row[k], W[k * DD + tid], acc);
    Ws_c[(size_t)rel * DD * DD + rrow * DD + tid] = acc;
    if (tid < HH) {  // head = tid
        float v = 0.f;
        for (int d = 0; d < 16; ++d)
            v += row[tid * 16 + d] * avec[rel * 256 + tid * 32 + 16 + d];
        VdstT[(rel * HH + tid) * DD + rrow] = v;
    }
    if (rrow == 0) {
        float b = 0.f;
        for (int k = 0; k < DD; ++k) b = fmaf(bpn[k], W[k * DD + tid], b);
        bs_c[rel * DD + tid] = b + bsrc[rel * DD + tid];
        if (rel == 0 && tid < 16) {
            int r2 = tid >> 3, h2 = tid & 7;
            float c2 = 0.f;
            for (int d = 0; d < 16; ++d)
                c2 += bpn[h2 * 16 + d] * avec[r2 * 256 + h2 * 32 + 16 + d];
            cdst[tid] = c2;
        }
    }
}

// ---- pack composed weights into MFMA B-fragment layout (bf16) ----
__global__ __launch_bounds__(256) void k_pack(
    const float* __restrict__ Ws_c, const float* __restrict__ Wres_c,
    const float* __restrict__ VdstT, short* __restrict__ Wpk) {
    const int t = blockIdx.x;
    const int kt = threadIdx.x >> 6;
    const int l = threadIdx.x & 63;
    const int c16 = l & 15;
    bf16x8 v;
    #pragma unroll
    for (int j = 0; j < 8; ++j) {
        int k = kt * 32 + (l >> 4) * 8 + j;
        float f;
        if (t < 24) {
            int m = t >> 3;                    // 0=Ws0, 1=Ws1, 2=Wres
            int col = (t & 7) * 16 + c16;
            const float* W = (m == 0) ? Ws_c : (m == 1) ? Ws_c + DD * DD : Wres_c;
            f = W[k * DD + col];
        } else {
            f = VdstT[c16 * DD + k];
        }
        v[j] = (short)f2bf(f);
    }
    *(bf16x8*)(Wpk + ((size_t)(t * 4 + kt) * 64 + l) * 8) = v;
}

// ---- node GEMM via MFMA: each wave owns MT=4 m-tiles (64 nodes), B reused 4x ----
__global__ __launch_bounds__(128) void k_node3(
    const float* __restrict__ x, const short* __restrict__ Wpk,
    const float* __restrict__ bs_c, const float* __restrict__ bres_c,
    const float* __restrict__ avec, const float* __restrict__ cdst,
    ushort_t* __restrict__ s_out, ushort_t* __restrict__ res_out,
    float* __restrict__ sc_src, float* __restrict__ sc_dst) {
    const int tid = threadIdx.x;
    const int l = tid & 63;
    const int w = tid >> 6;
    const int m16 = l & 15, g4 = l >> 4;
    const int mt0 = (blockIdx.x * 2 + w) * MT;

    bf16x8 af[MT][4];
    #pragma unroll
    for (int m = 0; m < MT; ++m) {
        int mt = mt0 + m;
        int node = (mt < MTOT ? mt : MTOT - 1) * 16 + m16;  // clamp OOB reads
        const float* xrow = x + (size_t)node * DD + g4 * 8;
        #pragma unroll
        for (int kt = 0; kt < 4; ++kt) {
            float4 v0 = *(const float4*)(xrow + kt * 32);
            float4 v1 = *(const float4*)(xrow + kt * 32 + 4);
            af[m][kt][0] = (short)f2bf(v0.x); af[m][kt][1] = (short)f2bf(v0.y);
            af[m][kt][2] = (short)f2bf(v0.z); af[m][kt][3] = (short)f2bf(v0.w);
            af[m][kt][4] = (short)f2bf(v1.x); af[m][kt][5] = (short)f2bf(v1.y);
            af[m][kt][6] = (short)f2bf(v1.z); af[m][kt][7] = (short)f2bf(v1.w);
        }
    }

    for (int t = 0; t < NT; ++t) {
        f32x4 acc[MT];
        #pragma unroll
        for (int m = 0; m < MT; ++m) acc[m] = (f32x4){0.f, 0.f, 0.f, 0.f};
        #pragma unroll
        for (int kt = 0; kt < 4; ++kt) {
            bf16x8 b = *(const bf16x8*)(Wpk + ((size_t)(t * 4 + kt) * 64 + l) * 8);
            #pragma unroll
            for (int m = 0; m < MT; ++m)
                acc[m] = __builtin_amdgcn_mfma_f32_16x16x32_bf16(af[m][kt], b, acc[m], 0, 0, 0);
        }
        #pragma unroll
        for (int m = 0; m < MT; ++m) {
            const int mt = mt0 + m;
            if (mt >= MTOT) continue;
            const int nb = mt * 16;
            if (t < 16) {
                const int rel = t >> 3, head = t & 7;
                const float a0v = avec[rel * 256 + head * 32 + m16];
                const float bb = bs_c[rel * DD + head * 16 + m16];
                #pragma unroll
                for (int r = 0; r < 4; ++r) {
                    const int node = nb + g4 * 4 + r;
                    float sv = acc[m][r] + bb;
                    s_out[((size_t)rel * NN + node) * DD + head * 16 + m16] = f2bf(sv);
                    float p = reduce16(sv * a0v);
                    if (m16 == 0) sc_src[((size_t)rel * NN + node) * HH + head] = p;
                }
            } else if (t < 24) {
                const int col = (t - 16) * 16 + m16;
                const float bb = bres_c[col];
                #pragma unroll
                for (int r = 0; r < 4; ++r) {
                    const int node = nb + g4 * 4 + r;
                    res_out[(size_t)node * DD + col] = f2bf(acc[m][r] + bb);
                }
            } else {
                const int rel = m16 >> 3, head = m16 & 7;
                const float bb = cdst[m16];
                #pragma unroll
                for (int r = 0; r < 4; ++r) {
                    const int node = nb + g4 * 4 + r;
                    sc_dst[((size_t)rel * NN + node) * HH + head] = acc[m][r] + bb;
                }
            }
        }
    }
}

// ---- CSR build ----
__global__ void k_zero(int* __restrict__ cnt) {
    int i = blockIdx.x * blockDim.x + threadIdx.x;
    if (i < RN) cnt[i] = 0;
}

__global__ void k_count(const int* __restrict__ dst, int* __restrict__ cnt) {
    int idx = blockIdx.x * blockDim.x + threadIdx.x;
    if (idx >= RR * EE) return;
    int r = idx / EE;
    atomicAdd(&cnt[r * NN + dst[idx]], 1);
}

__global__ __launch_bounds__(SCAN_CHUNK) void k_scan1(const int* __restrict__ cnt,
                                                      int* __restrict__ row_ptr,
                                                      int* __restrict__ blk) {
    __shared__ int sh[SCAN_CHUNK];
    const int tid = threadIdx.x;
    const int i = blockIdx.x * SCAN_CHUNK + tid;
    int v = (i < RN) ? cnt[i] : 0;
    sh[tid] = v;
    __syncthreads();
    for (int off = 1; off < SCAN_CHUNK; off <<= 1) {
        int t = (tid >= off) ? sh[tid - off] : 0;
        __syncthreads();
        sh[tid] += t;
        __syncthreads();
    }
    if (i < RN) row_ptr[i] = sh[tid] - v;
    if (tid == SCAN_CHUNK - 1) blk[blockIdx.x] = sh[tid];
}

__global__ __launch_bounds__(256) void k_scan2(int* __restrict__ blk) {
    __shared__ int sh[256];
    const int tid = threadIdx.x;
    int v = (tid < NBLK) ? blk[tid] : 0;
    sh[tid] = v;
    __syncthreads();
    for (int off = 1; off < 256; off <<= 1) {
        int t = (tid >= off) ? sh[tid - off] : 0;
        __syncthreads();
        sh[tid] += t;
        __syncthreads();
    }
    if (tid < NBLK) blk[tid] = sh[tid] - v;
}

__global__ void k_scan3(int* __restrict__ row_ptr, int* __restrict__ cursor,
                        const int* __restrict__ blk) {
    int i = blockIdx.x * blockDim.x + threadIdx.x;
    if (i < RN) {
        int v = row_ptr[i] + blk[i / SCAN_CHUNK];
        row_ptr[i] = v;
        cursor[i] = v;
    }
    if (i == 0) row_ptr[RN] = RR * EE;
}

// fill stores the SRC VALUE per CSR slot (no eid indirection in the gather)
__global__ void k_fill(const int* __restrict__ src, const int* __restrict__ dst,
                       int* __restrict__ cursor, int* __restrict__ esrc) {
    int idx = blockIdx.x * blockDim.x + threadIdx.x;
    if (idx >= RR * EE) return;
    int r = idx / EE;
    int pos = atomicAdd(&cursor[r * NN + dst[idx]], 1);
    esrc[pos] = src[idx];
}

// deterministic order: sort each segment by src value. LDS insertion sort for
// d <= SEGCAP (>99.99% of Poisson(6) segments), global selection sort else.
__global__ __launch_bounds__(256) void k_sortseg(const int* __restrict__ row_ptr,
                                                 int* __restrict__ esrc) {
    __shared__ int buf[256][SEGCAP + 1];   // +1 pad: avoid 2-bank aliasing
    int s = blockIdx.x * blockDim.x + threadIdx.x;
    if (s >= RN) return;
    int p0 = row_ptr[s], p1 = row_ptr[s + 1];
    int d = p1 - p0;
    if (d <= 1) return;
    if (d <= SEGCAP) {
        int* b = buf[threadIdx.x];
        for (int i = 0; i < d; ++i) b[i] = esrc[p0 + i];
        for (int i = 1; i < d; ++i) {
            int key = b[i];
            int k = i - 1;
            while (k >= 0 && b[k] > key) { b[k + 1] = b[k]; --k; }
            b[k + 1] = key;
        }
        for (int i = 0; i < d; ++i) esrc[p0 + i] = b[i];
    } else {
        for (int i = p0; i < p1 - 1; ++i) {
            int mn = esrc[i], mi = i;
            for (int k = i + 1; k < p1; ++k) {
                int v = esrc[k];
                if (v < mn) { mn = v; mi = k; }
            }
            esrc[mi] = esrc[i];
            esrc[i] = mn;
        }
    }
}

// ---- fused gather: single-pass softmax (no max shift) + agg + gate + cross ----
// exp without max subtraction: scores ~N(0,6), max over 10M samples ~30 << 88,
// alpha = e/den is mathematically identical to the max-shifted reference.
__global__ __launch_bounds__(256) void k_gather_cross(
    const int* __restrict__ esrc, const int* __restrict__ row_ptr,
    const float* __restrict__ sc_src, const float* __restrict__ sc_dst,
    const ushort_t* __restrict__ s, const ushort_t* __restrict__ res_buf,
    const float* __restrict__ res_alpha, const float* __restrict__ crossW,
    float* __restrict__ out) {
    int n = blockIdx.x * 4 + (threadIdx.x >> 6);
    if (n >= NN) return;
    const int lane = threadIdx.x & 63;
    const int g = lane >> 5;
    const int j = lane & 31;
    const int h = j >> 2;

    const int seg = g * NN + n;
    const int p0 = row_ptr[seg], p1 = row_ptr[seg + 1];
    const float sd = sc_dst[(size_t)seg * HH + h];

    float den = 0.f;
    float4 acc = {0.f, 0.f, 0.f, 0.f};
    int p = p0;
    for (; p + 1 < p1; p += 2) {
        int sr0 = esrc[p], sr1 = esrc[p + 1];
        ushort4 s40 = *(const ushort4*)(s + (size_t)(g * NN + sr0) * DD + j * 4);
        ushort4 s41 = *(const ushort4*)(s + (size_t)(g * NN + sr1) * DD + j * 4);
        float v0 = lrelu(sc_src[(size_t)(g * NN + sr0) * HH + h] + sd);
        float v1 = lrelu(sc_src[(size_t)(g * NN + sr1) * HH + h] + sd);
        float e0 = __expf(v0);
        float e1 = __expf(v1);
        den += e0; den += e1;
        acc.x = fmaf(e0, bf2f(s40.x), acc.x); acc.x = fmaf(e1, bf2f(s41.x), acc.x);
        acc.y = fmaf(e0, bf2f(s40.y), acc.y); acc.y = fmaf(e1, bf2f(s41.y), acc.y);
        acc.z = fmaf(e0, bf2f(s40.z), acc.z); acc.z = fmaf(e1, bf2f(s41.z), acc.z);
        acc.w = fmaf(e0, bf2f(s40.w), acc.w); acc.w = fmaf(e1, bf2f(s41.w), acc.w);
    }
    if (p < p1) {
        int sr0 = esrc[p];
        ushort4 s40 = *(const ushort4*)(s + (size_t)(g * NN + sr0) * DD + j * 4);
        float v0 = lrelu(sc_src[(size_t)(g * NN + sr0) * HH + h] + sd);
        float e0 = __expf(v0);
        den += e0;
        acc.x = fmaf(e0, bf2f(s40.x), acc.x);
        acc.y = fmaf(e0, bf2f(s40.y), acc.y);
        acc.z = fmaf(e0, bf2f(s40.z), acc.z);
        acc.w = fmaf(e0, bf2f(s40.w), acc.w);
    }
    float inv = (p1 > p0) ? 1.f / den : 0.f;

    float gate = 1.f / (1.f + __expf(-res_alpha[0]));
    ushort4 r4u = *(const ushort4*)(res_buf + (size_t)n * DD + j * 4);
    float4 og;
    og.x = fmaf(acc.x * inv, gate, bf2f(r4u.x) * (1.f - gate));
    og.y = fmaf(acc.y * inv, gate, bf2f(r4u.y) * (1.f - gate));
    og.z = fmaf(acc.z * inv, gate, bf2f(r4u.z) * (1.f - gate));
    og.w = fmaf(acc.w * inv, gate, bf2f(r4u.w) * (1.f - gate));

    float4 oo;
    oo.x = __shfl_xor(og.x, 32);
    oo.y = __shfl_xor(og.y, 32);
    oo.z = __shfl_xor(og.z, 32);
    oo.w = __shfl_xor(og.w, 32);

    float4 cw = *(const float4*)(crossW + g * DD + j * 4);
    float ds_ = og.x * cw.x + og.y * cw.y + og.z * cw.z + og.w * cw.w;
    float do_ = oo.x * cw.x + oo.y * cw.y + oo.z * cw.z + oo.w * cw.w;
    ds_ += __shfl_xor(ds_, 1); ds_ += __shfl_xor(ds_, 2);
    do_ += __shfl_xor(do_, 1); do_ += __shfl_xor(do_, 2);
    float l0 = lrelu(ds_), l1 = lrelu(do_);
    float mm = fmaxf(l0, l1);
    float e0 = __expf(l0 - mm), e1 = __expf(l1 - mm);
    float winv = 1.f / (e0 + e1);
    float w0 = e0 * winv, w1 = e1 * winv;

    float4 o;
    o.x = w0 * og.x + w1 * oo.x;
    o.y = w0 * og.y + w1 * oo.y;
    o.z = w0 * og.z + w1 * oo.z;
    o.w = w0 * og.w + w1 * oo.w;
    *(float4*)(out + (size_t)(g * NN + n) * DD + j * 4) = o;
}

extern "C" void kernel_launch(void* const* d_in, const int* in_sizes, int n_in,
                              void* d_out, int out_size, void* d_ws, size_t ws_size,
                              hipStream_t stream) {
    const float* x        = (const float*)d_in[0];
    const int*   src      = (const int*)d_in[1];
    const int*   dst      = (const int*)d_in[2];
    const float* rel_emb  = (const float*)d_in[3];
    const float* Wp       = (const float*)d_in[4];
    const float* bp       = (const float*)d_in[5];
    const float* Wn       = (const float*)d_in[6];
    const float* bn       = (const float*)d_in[7];
    const float* Wsrc     = (const float*)d_in[8];
    const float* bsrc     = (const float*)d_in[9];
    const float* Wrel     = (const float*)d_in[10];
    const float* resW     = (const float*)d_in[11];
    const float* resb     = (const float*)d_in[12];
    const float* res_alpha= (const float*)d_in[13];
    const float* crossW   = (const float*)d_in[14];
    const float* Wprop    = (const float*)d_in[15];
    const float* bprop    = (const float*)d_in[16];

    float* out = (float*)d_out;

    // workspace layout: bf16 buffers first, then f32, then packed weights, ints
    ushort_t* s_bf   = (ushort_t*)d_ws;                    // R*N*D ushorts
    ushort_t* res_bf = s_bf + (size_t)RR * NN * DD;        // N*D ushorts
    float* fbase   = (float*)(res_bf + (size_t)NN * DD);
    float* sc_src  = fbase;                                // R*N*H
    float* sc_dst  = sc_src  + (size_t)RR * NN * HH;       // R*N*H
    float* avec    = sc_dst  + (size_t)RR * NN * HH;       // 512
    float* Wpn     = avec    + 512;                        // 16384
    float* Wres_c  = Wpn     + DD * DD;                    // 16384
    float* Ws_c    = Wres_c  + DD * DD;                    // 2*16384
    float* VdstT   = Ws_c    + (size_t)RR * DD * DD;       // 16*128
    float* bpn     = VdstT   + 16 * DD;                    // 128
    float* bres_c  = bpn     + DD;                         // 128
    float* bs_c    = bres_c  + DD;                         // 256
    float* cdst    = bs_c    + RR * DD;                    // 16
    short* Wpk     = (short*)(cdst + 16);                  // 25*4*64*8 = 51200
    int*   cnt     = (int*)(Wpk + (size_t)NT * 4 * 64 * 8);// RN
    int*   row_ptr = cnt + RN;                             // RN + 1
    int*   cursor  = row_ptr + RN + 1;                     // RN
    int*   esrc    = cursor + RN;                          // R*E
    int*   blk     = esrc + RR * EE;                       // NBLK

    k_prep<<<1, 256, 0, stream>>>(rel_emb, Wrel, Wprop, bprop, avec,
                                  out + (size_t)RR * NN * DD);
    k_compose1<<<DD, DD, 0, stream>>>(Wp, bp, Wn, bn, resW, resb,
                                      Wpn, bpn, Wres_c, bres_c);
    k_compose2<<<dim3(RR, DD), DD, 0, stream>>>(Wpn, bpn, Wsrc, bsrc, avec,
                                                Ws_c, bs_c, VdstT, cdst);
    k_pack<<<NT, 256, 0, stream>>>(Ws_c, Wres_c, VdstT, Wpk);
    k_node3<<<(MTOT + 2 * MT - 1) / (2 * MT), 128, 0, stream>>>(
        x, Wpk, bs_c, bres_c, avec, cdst, s_bf, res_bf, sc_src, sc_dst);
    k_zero<<<(RN + 255) / 256, 256, 0, stream>>>(cnt);
    k_count<<<(RR * EE + 255) / 256, 256, 0, stream>>>(dst, cnt);
    k_scan1<<<NBLK, SCAN_CHUNK, 0, stream>>>(cnt, row_ptr, blk);
    k_scan2<<<1, 256, 0, stream>>>(blk);
    k_scan3<<<(RN + 255) / 256, 256, 0, stream>>>(row_ptr, cursor, blk);
    k_fill<<<(RR * EE + 255) / 256, 256, 0, stream>>>(src, dst, cursor, esrc);
    k_sortseg<<<(RN + 255) / 256, 256, 0, stream>>>(row_ptr, esrc);
    k_gather_cross<<<(NN + 3) / 4, 256, 0, stream>>>(esrc, row_ptr, sc_src, sc_dst,
                                                     s_bf, res_bf, res_alpha, crossW,
                                                     out);
}

// Round 9
// 343.773 us; speedup vs baseline: 9.7534x; 1.0846x over previous
//
#include <hip/hip_runtime.h>
#include <math.h>

#define NN 100000
#define EE 600000
#define RR 2
#define DD 128
#define HH 8
#define DHH 16
#define RN (RR * NN)
#define SCAN_CHUNK 1024
#define NBLK ((RN + SCAN_CHUNK - 1) / SCAN_CHUNK)   // 196
#define NT 26     // N-tiles: 8 (s0) + 8 (s1) + 8 (res) + 1 (sc_dst) + 1 (sc_src)
#define MTOT 6250 // total m-tiles (16 nodes each)
#define SEGCAP 16

typedef unsigned short ushort_t;
typedef short bf16x8 __attribute__((ext_vector_type(8)));
typedef float f32x4 __attribute__((ext_vector_type(4)));

__device__ __forceinline__ float lrelu(float v) { return v >= 0.f ? v : 0.2f * v; }

// f32 -> bf16 (round to nearest even), bf16 -> f32 (exact)
__device__ __forceinline__ ushort_t f2bf(float f) {
    unsigned int u = __float_as_uint(f);
    u = (u + 0x7FFFu + ((u >> 16) & 1u)) >> 16;
    return (ushort_t)u;
}
__device__ __forceinline__ float bf2f(ushort_t u) {
    return __uint_as_float(((unsigned int)u) << 16);
}

// ---- prep: a = rel_emb @ Wrel  [R*256], rel_out = rel_emb @ Wprop + bprop ----
__global__ void k_prep(const float* __restrict__ rel_emb, const float* __restrict__ Wrel,
                       const float* __restrict__ Wprop, const float* __restrict__ bprop,
                       float* __restrict__ avec, float* __restrict__ rel_out) {
    int tid = threadIdx.x;
    for (int idx = tid; idx < RR * 256; idx += 256) {
        int r = idx >> 8, o = idx & 255;
        float acc = 0.f;
        for (int i = 0; i < 64; ++i)
            acc += rel_emb[r * 64 + i] * Wrel[(r * 64 + i) * 256 + o];
        avec[idx] = acc;
    }
    {   // rel_out: 256 outputs, one per thread
        int r = tid >> 7, o = tid & 127;
        float acc = bprop[tid];
        for (int i = 0; i < 64; ++i)
            acc += rel_emb[r * 64 + i] * Wprop[(r * 64 + i) * 128 + o];
        rel_out[tid] = acc;
    }
}

// ---- compose stage 1: Wpn = Wp@Wn, Wres_c = Wp@resW (+ bias folds) ----
__global__ __launch_bounds__(128) void k_compose1(
    const float* __restrict__ Wp, const float* __restrict__ bp,
    const float* __restrict__ Wn, const float* __restrict__ bn,
    const float* __restrict__ resW, const float* __restrict__ resb,
    float* __restrict__ Wpn, float* __restrict__ bpn,
    float* __restrict__ Wres_c, float* __restrict__ bres_c) {
    __shared__ float row[DD];
    const int rrow = blockIdx.x, tid = threadIdx.x;
    row[tid] = Wp[rrow * DD + tid];
    __syncthreads();
    float acc1 = 0.f, acc2 = 0.f;
    for (int k = 0; k < DD; ++k) {
        float wv = row[k];
        acc1 = fmaf(wv, Wn[k * DD + tid], acc1);
        acc2 = fmaf(wv, resW[k * DD + tid], acc2);
    }
    Wpn[rrow * DD + tid] = acc1;
    Wres_c[rrow * DD + tid] = acc2;
    if (rrow == 0) {
        float b1 = 0.f, b2 = 0.f;
        for (int k = 0; k < DD; ++k) {
            b1 = fmaf(bp[k], Wn[k * DD + tid], b1);
            b2 = fmaf(bp[k], resW[k * DD + tid], b2);
        }
        bpn[tid] = b1 + bn[tid];
        bres_c[tid] = b2 + resb[tid];
    }
}

// ---- compose stage 2: Ws_c[r] = Wpn@Wsrc_r (+bias), VdstT = Wpn-projected a1 ----
__global__ __launch_bounds__(128) void k_compose2(
    const float* __restrict__ Wpn, const float* __restrict__ bpn,
    const float* __restrict__ Wsrc, const float* __restrict__ bsrc,
    const float* __restrict__ avec,
    float* __restrict__ Ws_c, float* __restrict__ bs_c,
    float* __restrict__ VdstT, float* __restrict__ cdst) {
    __shared__ float row[DD];
    const int rel = blockIdx.x, rrow = blockIdx.y, tid = threadIdx.x;
    row[tid] = Wpn[rrow * DD + tid];
    __syncthreads();
    const float* W = Wsrc + (size_t)rel * DD * DD;
    float acc = 0.f;
    for (int k = 0; k < DD; ++k) acc = fmaf(row[k], W[k * DD + tid], acc);
    Ws_c[(size_t)rel * DD * DD + rrow * DD + tid] = acc;
    if (tid < HH) {  // head = tid
        float v = 0.f;
        for (int d = 0; d < 16; ++d)
            v += row[tid * 16 + d] * avec[rel * 256 + tid * 32 + 16 + d];
        VdstT[(rel * HH + tid) * DD + rrow] = v;
    }
    if (rrow == 0) {
        float b = 0.f;
        for (int k = 0; k < DD; ++k) b = fmaf(bpn[k], W[k * DD + tid], b);
        bs_c[rel * DD + tid] = b + bsrc[rel * DD + tid];
        if (rel == 0 && tid < 16) {
            int r2 = tid >> 3, h2 = tid & 7;
            float c2 = 0.f;
            for (int d = 0; d < 16; ++d)
                c2 += bpn[h2 * 16 + d] * avec[r2 * 256 + h2 * 32 + 16 + d];
            cdst[tid] = c2;
        }
    }
}

// ---- pack composed weights into MFMA B-fragment layout (bf16) ----
// Tiles: t<24 -> [Ws0|Ws1|Wres] cols; t==24 -> VdstT; t==25 -> W_sc (sc_src
// projection: W_sc[k][r*8+h] = sum_d Ws_c[r][k][h*16+d] * a0[r][h][d]).
__global__ __launch_bounds__(256) void k_pack(
    const float* __restrict__ Ws_c, const float* __restrict__ Wres_c,
    const float* __restrict__ VdstT, const float* __restrict__ avec,
    const float* __restrict__ bs_c, short* __restrict__ Wpk,
    float* __restrict__ csrc) {
    const int t = blockIdx.x;
    const int kt = threadIdx.x >> 6;
    const int l = threadIdx.x & 63;
    const int c16 = l & 15;
    bf16x8 v;
    #pragma unroll
    for (int j = 0; j < 8; ++j) {
        int k = kt * 32 + (l >> 4) * 8 + j;
        float f;
        if (t < 24) {
            int m = t >> 3;                    // 0=Ws0, 1=Ws1, 2=Wres
            int col = (t & 7) * 16 + c16;
            const float* W = (m == 0) ? Ws_c : (m == 1) ? Ws_c + DD * DD : Wres_c;
            f = W[k * DD + col];
        } else if (t == 24) {
            f = VdstT[c16 * DD + k];
        } else {
            int rel = c16 >> 3, h = c16 & 7;
            f = 0.f;
            for (int d = 0; d < 16; ++d)
                f += Ws_c[(size_t)rel * DD * DD + k * DD + h * 16 + d]
                     * avec[rel * 256 + h * 32 + d];
        }
        v[j] = (short)f2bf(f);
    }
    *(bf16x8*)(Wpk + ((size_t)(t * 4 + kt) * 64 + l) * 8) = v;
    if (t == 25 && threadIdx.x < 16) {
        int rel = threadIdx.x >> 3, h = threadIdx.x & 7;
        float c = 0.f;
        for (int d = 0; d < 16; ++d)
            c += bs_c[rel * DD + h * 16 + d] * avec[rel * 256 + h * 32 + d];
        csrc[threadIdx.x] = c;
    }
}

// ---- node GEMM via MFMA: 4 waves/block, 1 m-tile (16 nodes) per wave ----
// A-frag: lane l row=l&15, k=(l>>4)*8+j.  D: col=l&15, row=(l>>4)*4+r.
__global__ __launch_bounds__(256) void k_node3(
    const float* __restrict__ x, const short* __restrict__ Wpk,
    const float* __restrict__ bs_c, const float* __restrict__ bres_c,
    const float* __restrict__ cdst, const float* __restrict__ csrc,
    ushort_t* __restrict__ s_out, ushort_t* __restrict__ res_out,
    float* __restrict__ sc_src, float* __restrict__ sc_dst) {
    const int tid = threadIdx.x;
    const int l = tid & 63;
    const int w = tid >> 6;
    const int m16 = l & 15, g4 = l >> 4;
    const int mt = blockIdx.x * 4 + w;
    const bool live = (mt < MTOT);
    const int nb = (live ? mt : MTOT - 1) * 16;

    bf16x8 af[4];
    const float* xrow = x + (size_t)(nb + m16) * DD + g4 * 8;
    #pragma unroll
    for (int kt = 0; kt < 4; ++kt) {
        float4 v0 = *(const float4*)(xrow + kt * 32);
        float4 v1 = *(const float4*)(xrow + kt * 32 + 4);
        af[kt][0] = (short)f2bf(v0.x); af[kt][1] = (short)f2bf(v0.y);
        af[kt][2] = (short)f2bf(v0.z); af[kt][3] = (short)f2bf(v0.w);
        af[kt][4] = (short)f2bf(v1.x); af[kt][5] = (short)f2bf(v1.y);
        af[kt][6] = (short)f2bf(v1.z); af[kt][7] = (short)f2bf(v1.w);
    }

    for (int t = 0; t < NT; ++t) {
        f32x4 acc = {0.f, 0.f, 0.f, 0.f};
        #pragma unroll
        for (int kt = 0; kt < 4; ++kt) {
            bf16x8 b = *(const bf16x8*)(Wpk + ((size_t)(t * 4 + kt) * 64 + l) * 8);
            acc = __builtin_amdgcn_mfma_f32_16x16x32_bf16(af[kt], b, acc, 0, 0, 0);
        }
        if (!live) continue;
        if (t < 16) {
            const int rel = t >> 3, head = t & 7;
            const float bb = bs_c[rel * DD + head * 16 + m16];
            #pragma unroll
            for (int r = 0; r < 4; ++r) {
                const int node = nb + g4 * 4 + r;
                s_out[((size_t)rel * NN + node) * DD + head * 16 + m16] =
                    f2bf(acc[r] + bb);
            }
        } else if (t < 24) {
            const int col = (t - 16) * 16 + m16;
            const float bb = bres_c[col];
            #pragma unroll
            for (int r = 0; r < 4; ++r) {
                const int node = nb + g4 * 4 + r;
                res_out[(size_t)node * DD + col] = f2bf(acc[r] + bb);
            }
        } else if (t == 24) {
            const int rel = m16 >> 3, head = m16 & 7;
            const float bb = cdst[m16];
            #pragma unroll
            for (int r = 0; r < 4; ++r) {
                const int node = nb + g4 * 4 + r;
                sc_dst[((size_t)rel * NN + node) * HH + head] = acc[r] + bb;
            }
        } else {
            const int rel = m16 >> 3, head = m16 & 7;
            const float bb = csrc[m16];
            #pragma unroll
            for (int r = 0; r < 4; ++r) {
                const int node = nb + g4 * 4 + r;
                sc_src[((size_t)rel * NN + node) * HH + head] = acc[r] + bb;
            }
        }
    }
}

// ---- CSR build ----
__global__ void k_zero(int* __restrict__ cnt) {
    int i = blockIdx.x * blockDim.x + threadIdx.x;
    if (i < RN) cnt[i] = 0;
}

__global__ void k_count(const int* __restrict__ dst, int* __restrict__ cnt) {
    int idx = blockIdx.x * blockDim.x + threadIdx.x;
    if (idx >= RR * EE) return;
    int r = idx / EE;
    atomicAdd(&cnt[r * NN + dst[idx]], 1);
}

__global__ __launch_bounds__(SCAN_CHUNK) void k_scan1(const int* __restrict__ cnt,
                                                      int* __restrict__ row_ptr,
                                                      int* __restrict__ blk) {
    __shared__ int sh[SCAN_CHUNK];
    const int tid = threadIdx.x;
    const int i = blockIdx.x * SCAN_CHUNK + tid;
    int v = (i < RN) ? cnt[i] : 0;
    sh[tid] = v;
    __syncthreads();
    for (int off = 1; off < SCAN_CHUNK; off <<= 1) {
        int t = (tid >= off) ? sh[tid - off] : 0;
        __syncthreads();
        sh[tid] += t;
        __syncthreads();
    }
    if (i < RN) row_ptr[i] = sh[tid] - v;
    if (tid == SCAN_CHUNK - 1) blk[blockIdx.x] = sh[tid];
}

__global__ __launch_bounds__(256) void k_scan2(int* __restrict__ blk) {
    __shared__ int sh[256];
    const int tid = threadIdx.x;
    int v = (tid < NBLK) ? blk[tid] : 0;
    sh[tid] = v;
    __syncthreads();
    for (int off = 1; off < 256; off <<= 1) {
        int t = (tid >= off) ? sh[tid - off] : 0;
        __syncthreads();
        sh[tid] += t;
        __syncthreads();
    }
    if (tid < NBLK) blk[tid] = sh[tid] - v;
}

__global__ void k_scan3(int* __restrict__ row_ptr, int* __restrict__ cursor,
                        const int* __restrict__ blk) {
    int i = blockIdx.x * blockDim.x + threadIdx.x;
    if (i < RN) {
        int v = row_ptr[i] + blk[i / SCAN_CHUNK];
        row_ptr[i] = v;
        cursor[i] = v;
    }
    if (i == 0) row_ptr[RN] = RR * EE;
}

// fill stores the SRC VALUE per CSR slot (no eid indirection in the gather)
__global__ void k_fill(const int* __restrict__ src, const int* __restrict__ dst,
                       int* __restrict__ cursor, int* __restrict__ esrc) {
    int idx = blockIdx.x * blockDim.x + threadIdx.x;
    if (idx >= RR * EE) return;
    int r = idx / EE;
    int pos = atomicAdd(&cursor[r * NN + dst[idx]], 1);
    esrc[pos] = src[idx];
}

// deterministic order: sort each segment by src value. LDS insertion sort for
// d <= SEGCAP (>99.99% of Poisson(6) segments), global selection sort else.
__global__ __launch_bounds__(256) void k_sortseg(const int* __restrict__ row_ptr,
                                                 int* __restrict__ esrc) {
    __shared__ int buf[256][SEGCAP + 1];   // +1 pad: avoid 2-bank aliasing
    int s = blockIdx.x * blockDim.x + threadIdx.x;
    if (s >= RN) return;
    int p0 = row_ptr[s], p1 = row_ptr[s + 1];
    int d = p1 - p0;
    if (d <= 1) return;
    if (d <= SEGCAP) {
        int* b = buf[threadIdx.x];
        for (int i = 0; i < d; ++i) b[i] = esrc[p0 + i];
        for (int i = 1; i < d; ++i) {
            int key = b[i];
            int k = i - 1;
            while (k >= 0 && b[k] > key) { b[k + 1] = b[k]; --k; }
            b[k + 1] = key;
        }
        for (int i = 0; i < d; ++i) esrc[p0 + i] = b[i];
    } else {
        for (int i = p0; i < p1 - 1; ++i) {
            int mn = esrc[i], mi = i;
            for (int k = i + 1; k < p1; ++k) {
                int v = esrc[k];
                if (v < mn) { mn = v; mi = k; }
            }
            esrc[mi] = esrc[i];
            esrc[i] = mn;
        }
    }
}

// ---- fused gather: single-pass softmax (no max shift) + agg + gate + cross ----
// exp without max subtraction: scores ~N(0,6), max over 10M samples ~30 << 88,
// alpha = e/den is mathematically identical to the max-shifted reference.
__global__ __launch_bounds__(256) void k_gather_cross(
    const int* __restrict__ esrc, const int* __restrict__ row_ptr,
    const float* __restrict__ sc_src, const float* __restrict__ sc_dst,
    const ushort_t* __restrict__ s, const ushort_t* __restrict__ res_buf,
    const float* __restrict__ res_alpha, const float* __restrict__ crossW,
    float* __restrict__ out) {
    int n = blockIdx.x * 4 + (threadIdx.x >> 6);
    if (n >= NN) return;
    const int lane = threadIdx.x & 63;
    const int g = lane >> 5;
    const int j = lane & 31;
    const int h = j >> 2;

    const int seg = g * NN + n;
    const int p0 = row_ptr[seg], p1 = row_ptr[seg + 1];
    const float sd = sc_dst[(size_t)seg * HH + h];

    float den = 0.f;
    float4 acc = {0.f, 0.f, 0.f, 0.f};
    int p = p0;
    for (; p + 1 < p1; p += 2) {
        int sr0 = esrc[p], sr1 = esrc[p + 1];
        ushort4 s40 = *(const ushort4*)(s + (size_t)(g * NN + sr0) * DD + j * 4);
        ushort4 s41 = *(const ushort4*)(s + (size_t)(g * NN + sr1) * DD + j * 4);
        float v0 = lrelu(sc_src[(size_t)(g * NN + sr0) * HH + h] + sd);
        float v1 = lrelu(sc_src[(size_t)(g * NN + sr1) * HH + h] + sd);
        float e0 = __expf(v0);
        float e1 = __expf(v1);
        den += e0; den += e1;
        acc.x = fmaf(e0, bf2f(s40.x), acc.x); acc.x = fmaf(e1, bf2f(s41.x), acc.x);
        acc.y = fmaf(e0, bf2f(s40.y), acc.y); acc.y = fmaf(e1, bf2f(s41.y), acc.y);
        acc.z = fmaf(e0, bf2f(s40.z), acc.z); acc.z = fmaf(e1, bf2f(s41.z), acc.z);
        acc.w = fmaf(e0, bf2f(s40.w), acc.w); acc.w = fmaf(e1, bf2f(s41.w), acc.w);
    }
    if (p < p1) {
        int sr0 = esrc[p];
        ushort4 s40 = *(const ushort4*)(s + (size_t)(g * NN + sr0) * DD + j * 4);
        float v0 = lrelu(sc_src[(size_t)(g * NN + sr0) * HH + h] + sd);
        float e0 = __expf(v0);
        den += e0;
        acc.x = fmaf(e0, bf2f(s40.x), acc.x);
        acc.y = fmaf(e0, bf2f(s40.y), acc.y);
        acc.z = fmaf(e0, bf2f(s40.z), acc.z);
        acc.w = fmaf(e0, bf2f(s40.w), acc.w);
    }
    float inv = (p1 > p0) ? 1.f / den : 0.f;

    float gate = 1.f / (1.f + __expf(-res_alpha[0]));
    ushort4 r4u = *(const ushort4*)(res_buf + (size_t)n * DD + j * 4);
    float4 og;
    og.x = fmaf(acc.x * inv, gate, bf2f(r4u.x) * (1.f - gate));
    og.y = fmaf(acc.y * inv, gate, bf2f(r4u.y) * (1.f - gate));
    og.z = fmaf(acc.z * inv, gate, bf2f(r4u.z) * (1.f - gate));
    og.w = fmaf(acc.w * inv, gate, bf2f(r4u.w) * (1.f - gate));

    float4 oo;
    oo.x = __shfl_xor(og.x, 32);
    oo.y = __shfl_xor(og.y, 32);
    oo.z = __shfl_xor(og.z, 32);
    oo.w = __shfl_xor(og.w, 32);

    float4 cw = *(const float4*)(crossW + g * DD + j * 4);
    float ds_ = og.x * cw.x + og.y * cw.y + og.z * cw.z + og.w * cw.w;
    float do_ = oo.x * cw.x + oo.y * cw.y + oo.z * cw.z + oo.w * cw.w;
    ds_ += __shfl_xor(ds_, 1); ds_ += __shfl_xor(ds_, 2);
    do_ += __shfl_xor(do_, 1); do_ += __shfl_xor(do_, 2);
    float l0 = lrelu(ds_), l1 = lrelu(do_);
    float mm = fmaxf(l0, l1);
    float e0 = __expf(l0 - mm), e1 = __expf(l1 - mm);
    float winv = 1.f / (e0 + e1);
    float w0 = e0 * winv, w1 = e1 * winv;

    float4 o;
    o.x = w0 * og.x + w1 * oo.x;
    o.y = w0 * og.y + w1 * oo.y;
    o.z = w0 * og.z + w1 * oo.z;
    o.w = w0 * og.w + w1 * oo.w;
    *(float4*)(out + (size_t)(g * NN + n) * DD + j * 4) = o;
}

extern "C" void kernel_launch(void* const* d_in, const int* in_sizes, int n_in,
                              void* d_out, int out_size, void* d_ws, size_t ws_size,
                              hipStream_t stream) {
    const float* x        = (const float*)d_in[0];
    const int*   src      = (const int*)d_in[1];
    const int*   dst      = (const int*)d_in[2];
    const float* rel_emb  = (const float*)d_in[3];
    const float* Wp       = (const float*)d_in[4];
    const float* bp       = (const float*)d_in[5];
    const float* Wn       = (const float*)d_in[6];
    const float* bn       = (const float*)d_in[7];
    const float* Wsrc     = (const float*)d_in[8];
    const float* bsrc     = (const float*)d_in[9];
    const float* Wrel     = (const float*)d_in[10];
    const float* resW     = (const float*)d_in[11];
    const float* resb     = (const float*)d_in[12];
    const float* res_alpha= (const float*)d_in[13];
    const float* crossW   = (const float*)d_in[14];
    const float* Wprop    = (const float*)d_in[15];
    const float* bprop    = (const float*)d_in[16];

    float* out = (float*)d_out;

    // workspace layout: bf16 buffers first, then f32, then packed weights, ints
    ushort_t* s_bf   = (ushort_t*)d_ws;                    // R*N*D ushorts
    ushort_t* res_bf = s_bf + (size_t)RR * NN * DD;        // N*D ushorts
    float* fbase   = (float*)(res_bf + (size_t)NN * DD);
    float* sc_src  = fbase;                                // R*N*H
    float* sc_dst  = sc_src  + (size_t)RR * NN * HH;       // R*N*H
    float* avec    = sc_dst  + (size_t)RR * NN * HH;       // 512
    float* Wpn     = avec    + 512;                        // 16384
    float* Wres_c  = Wpn     + DD * DD;                    // 16384
    float* Ws_c    = Wres_c  + DD * DD;                    // 2*16384
    float* VdstT   = Ws_c    + (size_t)RR * DD * DD;       // 16*128
    float* bpn     = VdstT   + 16 * DD;                    // 128
    float* bres_c  = bpn     + DD;                         // 128
    float* bs_c    = bres_c  + DD;                         // 256
    float* cdst    = bs_c    + RR * DD;                    // 16
    float* csrc    = cdst    + 16;                         // 16
    short* Wpk     = (short*)(csrc + 16);                  // 26*4*64*8
    int*   cnt     = (int*)(Wpk + (size_t)NT * 4 * 64 * 8);// RN
    int*   row_ptr = cnt + RN;                             // RN + 1
    int*   cursor  = row_ptr + RN + 1;                     // RN
    int*   esrc    = cursor + RN;                          // R*E
    int*   blk     = esrc + RR * EE;                       // NBLK

    k_prep<<<1, 256, 0, stream>>>(rel_emb, Wrel, Wprop, bprop, avec,
                                  out + (size_t)RR * NN * DD);
    k_compose1<<<DD, DD, 0, stream>>>(Wp, bp, Wn, bn, resW, resb,
                                      Wpn, bpn, Wres_c, bres_c);
    k_compose2<<<dim3(RR, DD), DD, 0, stream>>>(Wpn, bpn, Wsrc, bsrc, avec,
                                                Ws_c, bs_c, VdstT, cdst);
    k_pack<<<NT, 256, 0, stream>>>(Ws_c, Wres_c, VdstT, avec, bs_c, Wpk, csrc);
    k_node3<<<(MTOT + 3) / 4, 256, 0, stream>>>(
        x, Wpk, bs_c, bres_c, cdst, csrc, s_bf, res_bf, sc_src, sc_dst);
    k_zero<<<(RN + 255) / 256, 256, 0, stream>>>(cnt);
    k_count<<<(RR * EE + 255) / 256, 256, 0, stream>>>(dst, cnt);
    k_scan1<<<NBLK, SCAN_CHUNK, 0, stream>>>(cnt, row_ptr, blk);
    k_scan2<<<1, 256, 0, stream>>>(blk);
    k_scan3<<<(RN + 255) / 256, 256, 0, stream>>>(row_ptr, cursor, blk);
    k_fill<<<(RR * EE + 255) / 256, 256, 0, stream>>>(src, dst, cursor, esrc);
    k_sortseg<<<(RN + 255) / 256, 256, 0, stream>>>(row_ptr, esrc);
    k_gather_cross<<<(NN + 3) / 4, 256, 0, stream>>>(esrc, row_ptr, sc_src, sc_dst,
                                                     s_bf, res_bf, res_alpha, crossW,
                                                     out);
}